// Round 6
// baseline (451.852 us; speedup 1.0000x reference)
//
#include <hip/hip_runtime.h>
#include <hip/hip_bf16.h>
#include <cstdint>

typedef unsigned short ushort_t;
typedef __attribute__((ext_vector_type(8))) short short8;
typedef __attribute__((ext_vector_type(4))) short short4v;
typedef __attribute__((ext_vector_type(4))) float floatx4;
typedef __attribute__((ext_vector_type(4))) unsigned int uintx4;
typedef __attribute__((ext_vector_type(4))) unsigned short ushort4_t;

#define H_   16
#define DKV_ 64
#define DM_  1024
#define B_   2
#define NQ_  2048
#define NK_  2048

// fp32 -> bf16 round-to-nearest-even
__device__ __forceinline__ unsigned short f2bf(float f) {
  union { float f; unsigned int u; } v; v.f = f;
  unsigned int u = v.u;
  return (unsigned short)((u + 0x7fffu + ((u >> 16) & 1u)) >> 16);
}

// Trans ops via compiler-visible intrinsics (NOT inline asm) — R5-proven.
__device__ __forceinline__ float fexp2(float x) { return __builtin_amdgcn_exp2f(x); }
__device__ __forceinline__ float frcp(float x)  { return __builtin_amdgcn_rcpf(x); }

// packed fp32x2 -> bf16x2 (RTNE). No builtin on gfx950; asm is T12-proven in attn.
__device__ __forceinline__ unsigned int cvt_pk_bf16(float lo, float hi) {
  unsigned int r;
  asm("v_cvt_pk_bf16_f32 %0, %1, %2" : "=v"(r) : "v"(lo), "v"(hi));
  return r;
}

__device__ __forceinline__ floatx4 mfma16(short8 a, short8 b, floatx4 c) {
  return __builtin_amdgcn_mfma_f32_16x16x32_bf16(a, b, c, 0, 0, 0);
}

// async global->LDS, 16B per lane; LDS dest = wave-uniform base + lane*16
__device__ __forceinline__ void gload_lds16(const ushort_t* g, ushort_t* l) {
  __builtin_amdgcn_global_load_lds(
      (const __attribute__((address_space(1))) void*)g,
      (__attribute__((address_space(3))) void*)l, 16, 0, 0);
}

// ---------------- cast kernels (R7-proven) --------------------------------
__global__ __launch_bounds__(256) void cast_x_kernel(
    const float* __restrict__ q, const float* __restrict__ k,
    const float* __restrict__ v, ushort_t* __restrict__ dst)
{
  const int t = blockIdx.y;
  const float* src = (t == 0) ? q : (t == 1) ? k : v;
  ushort_t* d = dst + (size_t)t * 4096 * 1024;
  const int gid = blockIdx.x * 256 + threadIdx.x;
  #pragma unroll
  for (int u = 0; u < 8; u++) {
    const int i4 = u * 131072 + gid;
    floatx4 f = ((const floatx4*)src)[i4];
    ushort4_t o;
    #pragma unroll
    for (int e = 0; e < 4; e++) o[e] = f2bf(f[e]);
    *(ushort4_t*)&d[(size_t)i4 * 4] = o;
  }
}

__global__ __launch_bounds__(256) void cast_wt_kernel(
    const float* __restrict__ Wq, const float* __restrict__ Wk,
    const float* __restrict__ Wv, ushort_t* __restrict__ WtAll)
{
  __shared__ ushort_t tile[32][33];
  const int t = blockIdx.z;
  const float* W = (t == 0) ? Wq : (t == 1) ? Wk : Wv;
  ushort_t* Wt = WtAll + (size_t)t * 1024 * 1024;
  const int n0 = blockIdx.x * 32, k0 = blockIdx.y * 32;
  const int tid = threadIdx.x, r = tid >> 3, c4 = (tid & 7) * 4;
  floatx4 f = *(const floatx4*)&W[(size_t)(k0 + r) * 1024 + n0 + c4];
  #pragma unroll
  for (int e = 0; e < 4; e++) tile[r][c4 + e] = f2bf(f[e]);
  __syncthreads();
  ushort4_t o;
  #pragma unroll
  for (int e = 0; e < 4; e++) o[e] = tile[c4 + e][r];
  *(ushort4_t*)&Wt[(size_t)(n0 + r) * 1024 + k0 + c4] = o;
}

// ---------------- proj v2 (R7-proven; V-epilogue now sigma-permuted) ------
// Vt is written k-PERMUTED within each 64-k block so the attn kernel can
// read PV B-fragments directly from global with one 16B load:
// Vt[d][base + so(u)+e] = V[d][base + 8u+e']  (exactly the v9 LDS staging
// map, now baked into memory — bit-identical data per attn lane).
__global__ __launch_bounds__(256, 2) void proj_kernel2(
    const ushort_t* __restrict__ Xbf, const ushort_t* __restrict__ WtAll,
    const float* __restrict__ bq, const float* __restrict__ bk,
    const float* __restrict__ bv,
    ushort_t* __restrict__ Qb, ushort_t* __restrict__ Kb, ushort_t* __restrict__ Vt)
{
  const int mode = blockIdx.z;
  const ushort_t* X  = Xbf  + (size_t)mode * 4096 * 1024;
  const ushort_t* Wt = WtAll + (size_t)mode * 1024 * 1024;
  const float* bias  = (mode == 0) ? bq : (mode == 1) ? bk : bv;
  ushort_t* dst      = (mode == 0) ? Qb : (mode == 1) ? Kb : Vt;

  __shared__ ushort_t SM[8192];
  ushort_t* SA = SM;
  ushort_t* SB = SM + 4096;

  const int tid = threadIdx.x, lane = tid & 63, wid = tid >> 6;
  const int c = lane & 15, g = lane >> 4;
  const int m0 = blockIdx.y * 128, n0 = blockIdx.x * 128;
  const int wm = wid & 1, wn = wid >> 1, mb = wm * 64, nb = wn * 64;
  const int srow = lane >> 2;
  const int schunk = (lane & 3) * 8;

  floatx4 acc[4][4];
  #pragma unroll
  for (int i = 0; i < 4; i++)
    #pragma unroll
    for (int j = 0; j < 4; j++) acc[i][j] = floatx4{0.f, 0.f, 0.f, 0.f};

  for (int k0 = 0; k0 < DM_; k0 += 32) {
    __syncthreads();
    #pragma unroll
    for (int u = 0; u < 2; u++) {
      const int t = wid * 2 + u;
      gload_lds16(&X [(size_t)(m0 + t * 16 + srow) * 1024 + k0 + schunk], &SA[t * 512]);
      gload_lds16(&Wt[(size_t)(n0 + t * 16 + srow) * 1024 + k0 + schunk], &SB[t * 512]);
    }
    __syncthreads();

    short8 af[4], bfr[4];
    #pragma unroll
    for (int i = 0; i < 4; i++) af[i]  = *(const short8*)&SA[(mb + i * 16 + c) * 32 + g * 8];
    #pragma unroll
    for (int j = 0; j < 4; j++) bfr[j] = *(const short8*)&SB[(nb + j * 16 + c) * 32 + g * 8];
    #pragma unroll
    for (int i = 0; i < 4; i++)
      #pragma unroll
      for (int j = 0; j < 4; j++) acc[i][j] = mfma16(af[i], bfr[j], acc[i][j]);
  }

  __syncthreads();
  const float scale = (mode == 0) ? 0.18033688011112042f : 1.0f;
  ushort_t* EP = SM + wid * 2048;
  const int hh = (n0 + nb) >> 6;

  if (mode != 2) {
    for (int jj = 0; jj < 2; jj++) {
      #pragma unroll
      for (int jt = 0; jt < 2; jt++) {
        const int j = jj * 2 + jt;
        const float bb = bias[n0 + nb + j * 16 + c];
        #pragma unroll
        for (int i = 0; i < 4; i++)
          #pragma unroll
          for (int r = 0; r < 4; r++)
            EP[(i * 16 + g * 4 + r) * 32 + jt * 16 + c] =
                f2bf((acc[i][j][r] + bb) * scale);
      }
      #pragma unroll
      for (int u = 0; u < 8; u++) {
        const int rowl = u * 8 + (lane >> 3);
        ushort4_t vv = *(ushort4_t*)&EP[rowl * 32 + (lane & 7) * 4];
        const int rowg = m0 + mb + rowl;
        const int bb2 = rowg >> 11, nn = rowg & 2047;
        *(ushort4_t*)&dst[((size_t)(bb2 * H_ + hh) * NQ_ + nn) * DKV_ +
                          jj * 32 + (lane & 7) * 4] = vv;
      }
    }
  } else {
    const int bb2 = (m0 + mb) >> 11, nloc = (m0 + mb) & 2047;  // 64-aligned
    // sigma slots for this lane's k-chunk u2 = lane&7
    const int u2 = lane & 7;
    const int slo = 32 * (u2 >> 2) + 8 * ((2 * u2) & 3) + 4 * ((u2 >> 1) & 1);
    const int shi = 32 * (u2 >> 2) + 8 * ((2 * u2 + 1) & 3) + 4 * ((u2 >> 1) & 1);
    for (int j = 0; j < 4; j++) {
      const float bb = bias[n0 + nb + j * 16 + c];
      #pragma unroll
      for (int i = 0; i < 4; i++) {
        ushort4_t pk;
        #pragma unroll
        for (int r = 0; r < 4; r++) pk[r] = f2bf(acc[i][j][r] + bb);
        *(ushort4_t*)&EP[c * 72 + i * 16 + g * 4] = pk;
      }
      const int d0 = j * 16;
      #pragma unroll
      for (int u = 0; u < 2; u++) {
        const int coll = u * 8 + (lane >> 3);
        short8 vv = *(const short8*)&EP[coll * 72 + u2 * 8];
        short4v vl, vh;
        #pragma unroll
        for (int e = 0; e < 4; e++) { vl[e] = vv[e]; vh[e] = vv[4 + e]; }
        ushort_t* base = &dst[((size_t)(bb2 * H_ + hh) * DKV_ + d0 + coll) * NK_ + nloc];
        *(short4v*)&base[slo] = vl;
        *(short4v*)&base[shi] = vh;
      }
    }
  }
}

// ---------------- proj fallback (R2/R5-proven; V sigma-permute added) -----
constexpr int LDT = 40;
__global__ __launch_bounds__(256, 2) void proj_kernel_fb(
    const float* __restrict__ Xq, const float* __restrict__ Xk, const float* __restrict__ Xv,
    const float* __restrict__ Wq, const float* __restrict__ Wk, const float* __restrict__ Wv,
    const float* __restrict__ bq, const float* __restrict__ bk, const float* __restrict__ bv,
    ushort_t* __restrict__ Qb, ushort_t* __restrict__ Kb, ushort_t* __restrict__ Vt)
{
  const int mode = blockIdx.z;
  const float* X    = (mode == 0) ? Xq : (mode == 1) ? Xk : Xv;
  const float* W    = (mode == 0) ? Wq : (mode == 1) ? Wk : Wv;
  const float* bias = (mode == 0) ? bq : (mode == 1) ? bk : bv;
  ushort_t* dst     = (mode == 0) ? Qb : (mode == 1) ? Kb : Vt;

  __shared__ ushort_t Asm[128 * LDT];
  __shared__ ushort_t Bsm[128 * LDT];

  const int tid = threadIdx.x, lane = tid & 63, wid = tid >> 6;
  const int m0 = blockIdx.y * 128, n0 = blockIdx.x * 128;
  const int c = lane & 15, g = lane >> 4;
  const int wm = wid & 1, wn = wid >> 1, mb = wm * 64, nb = wn * 64;

  floatx4 acc[4][4];
  #pragma unroll
  for (int i = 0; i < 4; i++)
    #pragma unroll
    for (int j = 0; j < 4; j++) acc[i][j] = floatx4{0.f, 0.f, 0.f, 0.f};

  const int ar = tid >> 1, ah = tid & 1;
  const int bn = tid & 127, bh2 = tid >> 7;

  for (int k0 = 0; k0 < DM_; k0 += 32) {
    const floatx4* ap = (const floatx4*)(X + (size_t)(m0 + ar) * DM_ + k0 + ah * 16);
    floatx4 av0 = ap[0], av1 = ap[1], av2 = ap[2], av3 = ap[3];
    const float* wp = W + (size_t)(k0 + bh2 * 16) * 1024 + n0 + bn;
    float wv[16];
    #pragma unroll
    for (int j = 0; j < 16; j++) wv[j] = wp[j * 1024];
    short8 pa0, pa1, pb0, pb1;
    #pragma unroll
    for (int j = 0; j < 4; j++) {
      pa0[j] = (short)f2bf(av0[j]); pa0[4 + j] = (short)f2bf(av1[j]);
      pa1[j] = (short)f2bf(av2[j]); pa1[4 + j] = (short)f2bf(av3[j]);
    }
    #pragma unroll
    for (int j = 0; j < 8; j++) { pb0[j] = (short)f2bf(wv[j]); pb1[j] = (short)f2bf(wv[8 + j]); }
    __syncthreads();
    *(short8*)&Asm[ar * LDT + ah * 16]      = pa0;
    *(short8*)&Asm[ar * LDT + ah * 16 + 8]  = pa1;
    *(short8*)&Bsm[bn * LDT + bh2 * 16]     = pb0;
    *(short8*)&Bsm[bn * LDT + bh2 * 16 + 8] = pb1;
    __syncthreads();
    short8 af[4], bfr[4];
    #pragma unroll
    for (int i = 0; i < 4; i++) af[i]  = *(const short8*)&Asm[(mb + i * 16 + c) * LDT + g * 8];
    #pragma unroll
    for (int j = 0; j < 4; j++) bfr[j] = *(const short8*)&Bsm[(nb + j * 16 + c) * LDT + g * 8];
    #pragma unroll
    for (int i = 0; i < 4; i++)
      #pragma unroll
      for (int j = 0; j < 4; j++) acc[i][j] = mfma16(af[i], bfr[j], acc[i][j]);
  }
  #pragma unroll
  for (int j = 0; j < 4; j++) {
    const int col = n0 + nb + j * 16 + c;
    const float bv_ = bias[col];
    const int h = col >> 6, d = col & 63;
    #pragma unroll
    for (int i = 0; i < 4; i++)
      #pragma unroll
      for (int r = 0; r < 4; r++) {
        const int row = m0 + mb + i * 16 + g * 4 + r;
        const int b = row >> 11, n = row & 2047;
        float v = acc[i][j][r] + bv_;
        if (mode == 0) {
          v *= 0.18033688011112042f;
          dst[((size_t)(b * H_ + h) * NQ_ + n) * DKV_ + d] = f2bf(v);
        } else if (mode == 1) {
          dst[((size_t)(b * H_ + h) * NQ_ + n) * DKV_ + d] = f2bf(v);
        } else {
          const int tb = n & ~63, w = n & 63, u2 = w >> 3, e = w & 7;
          const int slo = 32 * (u2 >> 2) + 8 * ((2 * u2) & 3) + 4 * ((u2 >> 1) & 1);
          const int shi = 32 * (u2 >> 2) + 8 * ((2 * u2 + 1) & 3) + 4 * ((u2 >> 1) & 1);
          const int phys = tb + (e < 4 ? slo + e : shi + e - 4);
          dst[((size_t)(b * H_ + h) * DKV_ + d) * NK_ + phys] = f2bf(v);
        }
      }
  }
}

// ---------------- attn v10: no-LDS, barrier-free, independent waves -------
// R5 post-mortem: FETCH halved, time identical => not BW-bound at any level.
// Pipe-busy sum (LDS 59% + VALU 22% + MFMA 15% ~ 96%) says the per-tile
// barrier LOCKSTEPS all waves through the same phase => pipes serialize
// instead of overlapping (explains v4>v5 and v8 regression).
// v10 deletes the lockstep: K (8KB/tile) and sigma-permuted V (8KB/tile)
// are read DIRECTLY from global — L1-shared across the block's 8 waves,
// L2-resident via a (b,h)-co-locating XCD swizzle (4 bh-groups x 512KB =
// 2MB < 4MB L2/XCD). No LDS, no __syncthreads, waves fully independent
// (guide #7 / m169: don't stage what the cache holds). gp keeps a 1-tile
// register ping-pong (loads now genuinely span tiles — nothing drains them).
// T5 setprio around MFMA clusters (m191 regime: independent waves).
__global__ __launch_bounds__(512, 4) void attn_kernel(
    const ushort_t* __restrict__ Qb, const ushort_t* __restrict__ Kb,
    const ushort_t* __restrict__ Vt, const float* __restrict__ gp,
    float* __restrict__ out)
{
  constexpr int NT = NK_ / 64;                    // 32 tiles

  const int tid = threadIdx.x, lane = tid & 63, wid = tid >> 6;  // wid 0..7
  const int c = lane & 15, g = lane >> 4;

  // (b,h)-co-locating XCD swizzle: flat%8 ~ XCD under round-robin dispatch.
  // qy = i&15 varies fastest within an XCD => the 16 qy-blocks of one (b,h)
  // share that XCD's L2 (K/V resident); bh = xcd + 8*(i>>4).
  const int flat = blockIdx.x + (blockIdx.y << 4) + (blockIdx.z << 8); // 0..511
  const int xcd = flat & 7, i = flat >> 3;
  const int qy = i & 15;
  const int bh = xcd + ((i >> 4) << 3);           // 0..31
  const int b = bh >> 4, h = bh & 15;

  const int qw = qy * 128 + wid * 16;

  const ushort_t* Qp = Qb + (size_t)bh * NQ_ * DKV_;
  const ushort_t* Kp = Kb + (size_t)bh * NK_ * DKV_;
  const ushort_t* Vp = Vt + (size_t)bh * DKV_ * NK_;
  const float* gpq = gp + (size_t)b * NQ_ * NK_ + (size_t)(qw + c) * NK_;

  // Q fragments resident (pre-scaled by log2(e)/8)
  short8 qf[2];
  #pragma unroll
  for (int kc = 0; kc < 2; kc++)
    qf[kc] = *(const short8*)&Qp[(qw + c) * DKV_ + kc * 32 + g * 8];

  floatx4 o[4];
  float l = 0.f;
  #pragma unroll
  for (int jd = 0; jd < 4; jd++) o[jd] = floatx4{0.f, 0.f, 0.f, 0.f};

  // gp(0) prologue
  floatx4 gpA[4], gpB[4];
  #pragma unroll
  for (int jk = 0; jk < 4; jk++)
    gpA[jk] = *(const floatx4*)&gpq[jk * 16 + g * 4];

  // body: tile T gated by GPC; issue gp(T+1) into GPN early (spans the tile
  // body — no barrier ever drains it). K/V frags load directly (L1/L2-hot).
#define ATTN_BODY(T, GPC, GPN)                                               \
  {                                                                          \
    const int t_ = (T);                                                      \
    const int k0 = t_ * 64;                                                  \
    if (t_ + 1 < NT) {                                                       \
      const int k1 = k0 + 64;                                                \
      _Pragma("unroll")                                                      \
      for (int jk = 0; jk < 4; jk++)                                         \
        GPN[jk] = *(const floatx4*)&gpq[k1 + jk * 16 + g * 4];               \
    }                                                                        \
    /* S = K Q^T (log2 domain): lane holds q=c, k=jk*16+4g+r */              \
    floatx4 s_[4];                                                           \
    __builtin_amdgcn_s_setprio(1);                                           \
    _Pragma("unroll")                                                        \
    for (int jk = 0; jk < 4; jk++) {                                         \
      s_[jk] = floatx4{0.f, 0.f, 0.f, 0.f};                                  \
      _Pragma("unroll")                                                      \
      for (int kc = 0; kc < 2; kc++) {                                       \
        short8 kf = *(const short8*)&Kp[(size_t)(k0 + jk * 16 + c) * DKV_ +  \
                                        kc * 32 + g * 8];                    \
        s_[jk] = mfma16(kf, qf[kc], s_[jk]);                                 \
      }                                                                      \
    }                                                                        \
    __builtin_amdgcn_s_setprio(0);                                           \
    /* p = exp2(s); l += p; gate by gp; pack A-frags in-register */          \
    uintx4 afw_[2];                                                          \
    _Pragma("unroll")                                                        \
    for (int jk = 0; jk < 4; jk++) {                                         \
      const float p0 = fexp2(s_[jk][0]);                                     \
      const float p1 = fexp2(s_[jk][1]);                                     \
      const float p2 = fexp2(s_[jk][2]);                                     \
      const float p3 = fexp2(s_[jk][3]);                                     \
      l += (p0 + p1) + (p2 + p3);                                            \
      const unsigned int w0 = cvt_pk_bf16(p0 * GPC[jk][0], p1 * GPC[jk][1]); \
      const unsigned int w1 = cvt_pk_bf16(p2 * GPC[jk][2], p3 * GPC[jk][3]); \
      afw_[jk >> 1][2 * (jk & 1) + 0] = w0;                                  \
      afw_[jk >> 1][2 * (jk & 1) + 1] = w1;                                  \
    }                                                                        \
    /* PV: A = in-register P frags, B = sigma-permuted V direct from L2 */   \
    __builtin_amdgcn_s_setprio(1);                                           \
    _Pragma("unroll")                                                        \
    for (int kc = 0; kc < 2; kc++) {                                         \
      const short8 af_ = __builtin_bit_cast(short8, afw_[kc]);               \
      _Pragma("unroll")                                                      \
      for (int jd = 0; jd < 4; jd++) {                                       \
        short8 vf = *(const short8*)&Vp[(size_t)(jd * 16 + c) * NK_ + k0 +   \
                                        kc * 32 + g * 8];                    \
        o[jd] = mfma16(af_, vf, o[jd]);                                      \
      }                                                                      \
    }                                                                        \
    __builtin_amdgcn_s_setprio(0);                                           \
  }

  for (int tt = 0; tt < NT; tt += 2) {
    ATTN_BODY(tt,     gpA, gpB)
    ATTN_BODY(tt + 1, gpB, gpA)
  }
#undef ATTN_BODY

  // l lives per q=c; reduce across the 4 g-groups, then redistribute to the
  // output layout's q = 4g + r via shfl (once per kernel).
  float lf = l;
  lf += __shfl_xor(lf, 16);
  lf += __shfl_xor(lf, 32);
  const float inv = frcp(lf);
  float invr[4];
  #pragma unroll
  for (int r = 0; r < 4; r++) invr[r] = __shfl(inv, g * 4 + r);

  #pragma unroll
  for (int jd = 0; jd < 4; jd++)
    #pragma unroll
    for (int r = 0; r < 4; r++) {
      const int row = qw + g * 4 + r;
      out[(size_t)(b * NQ_ + row) * 1024 + h * 64 + jd * 16 + c] =
          o[jd][r] * invr[r];
    }
}

extern "C" void kernel_launch(void* const* d_in, const int* in_sizes, int n_in,
                              void* d_out, int out_size, void* d_ws, size_t ws_size,
                              hipStream_t stream) {
  const float* queries = (const float*)d_in[0];
  const float* keys    = (const float*)d_in[1];
  const float* values  = (const float*)d_in[2];
  const float* gp      = (const float*)d_in[3];
  // d_in[4] attention_mask: intentionally unused (reference discards it)
  const float* Wq = (const float*)d_in[5];
  const float* bq = (const float*)d_in[6];
  const float* Wk = (const float*)d_in[7];
  const float* bk = (const float*)d_in[8];
  const float* Wv = (const float*)d_in[9];
  const float* bv = (const float*)d_in[10];

  const size_t SZ_QKV = (size_t)3 * B_ * H_ * NQ_ * DKV_;  // shorts
  const size_t SZ_X   = (size_t)3 * 4096 * 1024;
  const size_t SZ_W   = (size_t)3 * 1024 * 1024;
  const size_t NEED   = (SZ_QKV + SZ_X + SZ_W) * sizeof(ushort_t);

  ushort_t* Qb = (ushort_t*)d_ws;                       // [B,H,NQ,64] bf16, pre-scaled
  ushort_t* Kb = Qb + (size_t)B_ * H_ * NQ_ * DKV_;     // [B,H,NK,64] bf16
  ushort_t* Vt = Kb + (size_t)B_ * H_ * NK_ * DKV_;     // [B,H,64,NK] bf16, sigma-permuted
  float* out = (float*)d_out;

  if (ws_size >= NEED) {
    ushort_t* Xbf = Qb + SZ_QKV;
    ushort_t* Wt  = Xbf + SZ_X;
    cast_x_kernel<<<dim3(512, 3), 256, 0, stream>>>(queries, keys, values, Xbf);
    cast_wt_kernel<<<dim3(32, 32, 3), 256, 0, stream>>>(Wq, Wk, Wv, Wt);
    proj_kernel2<<<dim3(8, 32, 3), 256, 0, stream>>>(
        Xbf, Wt, bq, bk, bv, Qb, Kb, Vt);
  } else {
    proj_kernel_fb<<<dim3(8, 32, 3), 256, 0, stream>>>(
        queries, keys, values, Wq, Wk, Wv, bq, bk, bv, Qb, Kb, Vt);
  }
  attn_kernel<<<dim3(H_, NQ_ / 128, B_), 512, 0, stream>>>(Qb, Kb, Vt, gp, out);
}

// Round 7
// 253.682 us; speedup vs baseline: 1.7812x; 1.7812x over previous
//
#include <hip/hip_runtime.h>
#include <hip/hip_bf16.h>
#include <cstdint>

typedef unsigned short ushort_t;
typedef __attribute__((ext_vector_type(8))) short short8;
typedef __attribute__((ext_vector_type(4))) float floatx4;
typedef __attribute__((ext_vector_type(4))) unsigned short ushort4_t;

#define H_   16
#define DKV_ 64
#define DM_  1024
#define B_   2
#define NQ_  2048
#define NK_  2048

// fp32 -> bf16 round-to-nearest-even
__device__ __forceinline__ unsigned short f2bf(float f) {
  union { float f; unsigned int u; } v; v.f = f;
  unsigned int u = v.u;
  return (unsigned short)((u + 0x7fffu + ((u >> 16) & 1u)) >> 16);
}

// Trans ops via compiler-visible intrinsics (NOT inline asm) — R5-proven.
__device__ __forceinline__ float fexp2(float x) { return __builtin_amdgcn_exp2f(x); }
__device__ __forceinline__ float frcp(float x)  { return __builtin_amdgcn_rcpf(x); }

__device__ __forceinline__ floatx4 mfma16(short8 a, short8 b, floatx4 c) {
  return __builtin_amdgcn_mfma_f32_16x16x32_bf16(a, b, c, 0, 0, 0);
}

// async global->LDS, 16B per lane; LDS dest = wave-uniform base + lane*16
__device__ __forceinline__ void gload_lds16(const ushort_t* g, ushort_t* l) {
  __builtin_amdgcn_global_load_lds(
      (const __attribute__((address_space(1))) void*)g,
      (__attribute__((address_space(3))) void*)l, 16, 0, 0);
}

// ---------------- cast kernels (R7-proven) --------------------------------
__global__ __launch_bounds__(256) void cast_x_kernel(
    const float* __restrict__ q, const float* __restrict__ k,
    const float* __restrict__ v, ushort_t* __restrict__ dst)
{
  const int t = blockIdx.y;
  const float* src = (t == 0) ? q : (t == 1) ? k : v;
  ushort_t* d = dst + (size_t)t * 4096 * 1024;
  const int gid = blockIdx.x * 256 + threadIdx.x;
  #pragma unroll
  for (int u = 0; u < 8; u++) {
    const int i4 = u * 131072 + gid;
    floatx4 f = ((const floatx4*)src)[i4];
    ushort4_t o;
    #pragma unroll
    for (int e = 0; e < 4; e++) o[e] = f2bf(f[e]);
    *(ushort4_t*)&d[(size_t)i4 * 4] = o;
  }
}

__global__ __launch_bounds__(256) void cast_wt_kernel(
    const float* __restrict__ Wq, const float* __restrict__ Wk,
    const float* __restrict__ Wv, ushort_t* __restrict__ WtAll)
{
  __shared__ ushort_t tile[32][33];
  const int t = blockIdx.z;
  const float* W = (t == 0) ? Wq : (t == 1) ? Wk : Wv;
  ushort_t* Wt = WtAll + (size_t)t * 1024 * 1024;
  const int n0 = blockIdx.x * 32, k0 = blockIdx.y * 32;
  const int tid = threadIdx.x, r = tid >> 3, c4 = (tid & 7) * 4;
  floatx4 f = *(const floatx4*)&W[(size_t)(k0 + r) * 1024 + n0 + c4];
  #pragma unroll
  for (int e = 0; e < 4; e++) tile[r][c4 + e] = f2bf(f[e]);
  __syncthreads();
  ushort4_t o;
  #pragma unroll
  for (int e = 0; e < 4; e++) o[e] = tile[c4 + e][r];
  *(ushort4_t*)&Wt[(size_t)(n0 + r) * 1024 + k0 + c4] = o;
}

// ---------------- proj v2 (R7-proven, byte-identical, R0 layout) ----------
__global__ __launch_bounds__(256, 2) void proj_kernel2(
    const ushort_t* __restrict__ Xbf, const ushort_t* __restrict__ WtAll,
    const float* __restrict__ bq, const float* __restrict__ bk,
    const float* __restrict__ bv,
    ushort_t* __restrict__ Qb, ushort_t* __restrict__ Kb, ushort_t* __restrict__ Vt)
{
  const int mode = blockIdx.z;
  const ushort_t* X  = Xbf  + (size_t)mode * 4096 * 1024;
  const ushort_t* Wt = WtAll + (size_t)mode * 1024 * 1024;
  const float* bias  = (mode == 0) ? bq : (mode == 1) ? bk : bv;
  ushort_t* dst      = (mode == 0) ? Qb : (mode == 1) ? Kb : Vt;

  __shared__ ushort_t SM[8192];
  ushort_t* SA = SM;
  ushort_t* SB = SM + 4096;

  const int tid = threadIdx.x, lane = tid & 63, wid = tid >> 6;
  const int c = lane & 15, g = lane >> 4;
  const int m0 = blockIdx.y * 128, n0 = blockIdx.x * 128;
  const int wm = wid & 1, wn = wid >> 1, mb = wm * 64, nb = wn * 64;
  const int srow = lane >> 2;
  const int schunk = (lane & 3) * 8;

  floatx4 acc[4][4];
  #pragma unroll
  for (int i = 0; i < 4; i++)
    #pragma unroll
    for (int j = 0; j < 4; j++) acc[i][j] = floatx4{0.f, 0.f, 0.f, 0.f};

  for (int k0 = 0; k0 < DM_; k0 += 32) {
    __syncthreads();
    #pragma unroll
    for (int u = 0; u < 2; u++) {
      const int t = wid * 2 + u;
      gload_lds16(&X [(size_t)(m0 + t * 16 + srow) * 1024 + k0 + schunk], &SA[t * 512]);
      gload_lds16(&Wt[(size_t)(n0 + t * 16 + srow) * 1024 + k0 + schunk], &SB[t * 512]);
    }
    __syncthreads();

    short8 af[4], bfr[4];
    #pragma unroll
    for (int i = 0; i < 4; i++) af[i]  = *(const short8*)&SA[(mb + i * 16 + c) * 32 + g * 8];
    #pragma unroll
    for (int j = 0; j < 4; j++) bfr[j] = *(const short8*)&SB[(nb + j * 16 + c) * 32 + g * 8];
    #pragma unroll
    for (int i = 0; i < 4; i++)
      #pragma unroll
      for (int j = 0; j < 4; j++) acc[i][j] = mfma16(af[i], bfr[j], acc[i][j]);
  }

  __syncthreads();
  const float scale = (mode == 0) ? 0.18033688011112042f : 1.0f;
  ushort_t* EP = SM + wid * 2048;
  const int hh = (n0 + nb) >> 6;

  if (mode != 2) {
    for (int jj = 0; jj < 2; jj++) {
      #pragma unroll
      for (int jt = 0; jt < 2; jt++) {
        const int j = jj * 2 + jt;
        const float bb = bias[n0 + nb + j * 16 + c];
        #pragma unroll
        for (int i = 0; i < 4; i++)
          #pragma unroll
          for (int r = 0; r < 4; r++)
            EP[(i * 16 + g * 4 + r) * 32 + jt * 16 + c] =
                f2bf((acc[i][j][r] + bb) * scale);
      }
      #pragma unroll
      for (int u = 0; u < 8; u++) {
        const int rowl = u * 8 + (lane >> 3);
        ushort4_t vv = *(ushort4_t*)&EP[rowl * 32 + (lane & 7) * 4];
        const int rowg = m0 + mb + rowl;
        const int bb2 = rowg >> 11, nn = rowg & 2047;
        *(ushort4_t*)&dst[((size_t)(bb2 * H_ + hh) * NQ_ + nn) * DKV_ +
                          jj * 32 + (lane & 7) * 4] = vv;
      }
    }
  } else {
    const int bb2 = (m0 + mb) >> 11, nloc = (m0 + mb) & 2047;
    for (int j = 0; j < 4; j++) {
      const float bb = bias[n0 + nb + j * 16 + c];
      #pragma unroll
      for (int i = 0; i < 4; i++) {
        ushort4_t pk;
        #pragma unroll
        for (int r = 0; r < 4; r++) pk[r] = f2bf(acc[i][j][r] + bb);
        *(ushort4_t*)&EP[c * 72 + i * 16 + g * 4] = pk;
      }
      const int d0 = j * 16;
      #pragma unroll
      for (int u = 0; u < 2; u++) {
        const int coll = u * 8 + (lane >> 3);
        short8 vv = *(const short8*)&EP[coll * 72 + (lane & 7) * 8];
        *(short8*)&dst[((size_t)(bb2 * H_ + hh) * DKV_ + d0 + coll) * NK_ +
                       nloc + (lane & 7) * 8] = vv;
      }
    }
  }
}

// ---------------- proj fallback (R2/R5-proven, R0 layout) -----------------
constexpr int LDT = 40;
__global__ __launch_bounds__(256, 2) void proj_kernel_fb(
    const float* __restrict__ Xq, const float* __restrict__ Xk, const float* __restrict__ Xv,
    const float* __restrict__ Wq, const float* __restrict__ Wk, const float* __restrict__ Wv,
    const float* __restrict__ bq, const float* __restrict__ bk, const float* __restrict__ bv,
    ushort_t* __restrict__ Qb, ushort_t* __restrict__ Kb, ushort_t* __restrict__ Vt)
{
  const int mode = blockIdx.z;
  const float* X    = (mode == 0) ? Xq : (mode == 1) ? Xk : Xv;
  const float* W    = (mode == 0) ? Wq : (mode == 1) ? Wk : Wv;
  const float* bias = (mode == 0) ? bq : (mode == 1) ? bk : bv;
  ushort_t* dst     = (mode == 0) ? Qb : (mode == 1) ? Kb : Vt;

  __shared__ ushort_t Asm[128 * LDT];
  __shared__ ushort_t Bsm[128 * LDT];

  const int tid = threadIdx.x, lane = tid & 63, wid = tid >> 6;
  const int m0 = blockIdx.y * 128, n0 = blockIdx.x * 128;
  const int c = lane & 15, g = lane >> 4;
  const int wm = wid & 1, wn = wid >> 1, mb = wm * 64, nb = wn * 64;

  floatx4 acc[4][4];
  #pragma unroll
  for (int i = 0; i < 4; i++)
    #pragma unroll
    for (int j = 0; j < 4; j++) acc[i][j] = floatx4{0.f, 0.f, 0.f, 0.f};

  const int ar = tid >> 1, ah = tid & 1;
  const int bn = tid & 127, bh2 = tid >> 7;

  for (int k0 = 0; k0 < DM_; k0 += 32) {
    const floatx4* ap = (const floatx4*)(X + (size_t)(m0 + ar) * DM_ + k0 + ah * 16);
    floatx4 av0 = ap[0], av1 = ap[1], av2 = ap[2], av3 = ap[3];
    const float* wp = W + (size_t)(k0 + bh2 * 16) * 1024 + n0 + bn;
    float wv[16];
    #pragma unroll
    for (int j = 0; j < 16; j++) wv[j] = wp[j * 1024];
    short8 pa0, pa1, pb0, pb1;
    #pragma unroll
    for (int j = 0; j < 4; j++) {
      pa0[j] = (short)f2bf(av0[j]); pa0[4 + j] = (short)f2bf(av1[j]);
      pa1[j] = (short)f2bf(av2[j]); pa1[4 + j] = (short)f2bf(av3[j]);
    }
    #pragma unroll
    for (int j = 0; j < 8; j++) { pb0[j] = (short)f2bf(wv[j]); pb1[j] = (short)f2bf(wv[8 + j]); }
    __syncthreads();
    *(short8*)&Asm[ar * LDT + ah * 16]      = pa0;
    *(short8*)&Asm[ar * LDT + ah * 16 + 8]  = pa1;
    *(short8*)&Bsm[bn * LDT + bh2 * 16]     = pb0;
    *(short8*)&Bsm[bn * LDT + bh2 * 16 + 8] = pb1;
    __syncthreads();
    short8 af[4], bfr[4];
    #pragma unroll
    for (int i = 0; i < 4; i++) af[i]  = *(const short8*)&Asm[(mb + i * 16 + c) * LDT + g * 8];
    #pragma unroll
    for (int j = 0; j < 4; j++) bfr[j] = *(const short8*)&Bsm[(nb + j * 16 + c) * LDT + g * 8];
    #pragma unroll
    for (int i = 0; i < 4; i++)
      #pragma unroll
      for (int j = 0; j < 4; j++) acc[i][j] = mfma16(af[i], bfr[j], acc[i][j]);
  }
  #pragma unroll
  for (int j = 0; j < 4; j++) {
    const int col = n0 + nb + j * 16 + c;
    const float bv_ = bias[col];
    const int h = col >> 6, d = col & 63;
    #pragma unroll
    for (int i = 0; i < 4; i++)
      #pragma unroll
      for (int r = 0; r < 4; r++) {
        const int row = m0 + mb + i * 16 + g * 4 + r;
        const int b = row >> 11, n = row & 2047;
        float v = acc[i][j][r] + bv_;
        if (mode == 0) {
          v *= 0.18033688011112042f;
          dst[((size_t)(b * H_ + h) * NQ_ + n) * DKV_ + d] = f2bf(v);
        } else if (mode == 1) {
          dst[((size_t)(b * H_ + h) * NQ_ + n) * DKV_ + d] = f2bf(v);
        } else {
          dst[((size_t)(b * H_ + h) * DKV_ + d) * NK_ + n] = f2bf(v);
        }
      }
  }
}

// ---------------- attn v11: v4 structure, 32 q/wave (shared K/V frags) ----
// R6 post-mortem: no-LDS direct-global K/V = 3.2x regression (L1/TA port
// saturated: 8 waves x 16KB/tile private fragment loads). LDS staging's
// 1-copy-in/8-readers-out is essential. v4 budget audit: LDS pipe ~88% busy
// (18 b128-reads/wave-tile serving only 16 q) — the saturated resource.
// v11 = v4 widened to 32 q/wave: each kf/vf LDS fragment feeds TWO MFMAs
// (q-halves), halving LDS-read work per output. 4 waves x 32q = 128 q/block,
// grid unchanged (512, 2/CU). P swizzle (gx16/prd) invariant under +16-row
// offset (row>>3 bit unchanged mod 2). All math byte-identical to v4.
__global__ __launch_bounds__(256, 2) void attn_kernel(
    const ushort_t* __restrict__ Qb, const ushort_t* __restrict__ Kb,
    const ushort_t* __restrict__ Vt, const float* __restrict__ gp,
    float* __restrict__ out)
{
  __shared__ ushort_t Ks[2][64 * 72];
  __shared__ ushort_t Vs[2][64 * 72];
  __shared__ ushort_t Pl[4][32 * 72];

  const int tid = threadIdx.x, lane = tid & 63, wid = tid >> 6;  // wid 0..3
  const int c = lane & 15, g = lane >> 4;
  const int h = blockIdx.x, b = blockIdx.z;       // h fastest: gp L2 locality
  const int bh = b * H_ + h;
  const int qw = blockIdx.y * 128 + wid * 32;

  const ushort_t* Qp = Qb + (size_t)bh * NQ_ * DKV_;
  const ushort_t* Kp = Kb + (size_t)bh * NK_ * DKV_;
  const ushort_t* Vp = Vt + (size_t)bh * DKV_ * NK_;
  const float* gpp = gp + (size_t)b * NQ_ * NK_ + (size_t)qw * NK_;
  ushort_t* Pw = Pl[wid];

  const int gx16 = (g >> 1) << 4;                 // write-side granule XOR
  const int prd  = g ^ (((c >> 3) & 1) << 1);     // read-side swizzled g

  // cooperative staging: 256 threads cover 64x64, 2 chunks each for K and V
  const int srow = tid >> 2;                      // 0..63
  const int scol = (tid & 3) * 8;                 // chunks scol and scol+32

  // Q fragments resident (pre-scaled by log2(e)/8): 2 q-halves
  short8 qf[2][2];
  #pragma unroll
  for (int qh = 0; qh < 2; qh++)
    #pragma unroll
    for (int kc = 0; kc < 2; kc++)
      qf[qh][kc] = *(const short8*)&Qp[(qw + qh * 16 + c) * DKV_ + kc * 32 + g * 8];

  // stage tile 0
  *(short8*)&Ks[0][srow * 72 + scol]      = *(const short8*)&Kp[(size_t)srow * DKV_ + scol];
  *(short8*)&Ks[0][srow * 72 + scol + 32] = *(const short8*)&Kp[(size_t)srow * DKV_ + scol + 32];
  *(short8*)&Vs[0][srow * 72 + scol]      = *(const short8*)&Vp[(size_t)srow * NK_ + scol];
  *(short8*)&Vs[0][srow * 72 + scol + 32] = *(const short8*)&Vp[(size_t)srow * NK_ + scol + 32];
  __syncthreads();

  floatx4 o[2][4];
  float l[2][4];
  #pragma unroll
  for (int qh = 0; qh < 2; qh++) {
    #pragma unroll
    for (int jd = 0; jd < 4; jd++) o[qh][jd] = floatx4{0.f, 0.f, 0.f, 0.f};
    #pragma unroll
    for (int r = 0; r < 4; r++) l[qh][r] = 0.f;
  }

  for (int t = 0; t < NK_ / 64; t++) {
    const int k0 = t * 64;
    const int cur = t & 1, nxt = cur ^ 1;

    // gp gathers first (consumed after S-MFMA), both q-halves
    float gpv[2][4][4];
    #pragma unroll
    for (int qh = 0; qh < 2; qh++)
      #pragma unroll
      for (int r = 0; r < 4; r++) {
        const float* gq = gpp + (size_t)(qh * 16 + g * 4 + r) * NK_ + k0 + c;
        #pragma unroll
        for (int jk = 0; jk < 4; jk++) gpv[qh][jk][r] = gq[jk * 16];
      }

    // issue next tile's staging loads (latency covered by whole body)
    short8 knx0, knx1, vnx0, vnx1;
    const bool has_next = (t + 1) < NK_ / 64;
    if (has_next) {
      const int k1 = k0 + 64;
      knx0 = *(const short8*)&Kp[(size_t)(k1 + srow) * DKV_ + scol];
      knx1 = *(const short8*)&Kp[(size_t)(k1 + srow) * DKV_ + scol + 32];
      vnx0 = *(const short8*)&Vp[(size_t)srow * NK_ + k1 + scol];
      vnx1 = *(const short8*)&Vp[(size_t)srow * NK_ + k1 + scol + 32];
    }

    // S = Q K^T (log2 domain), K from LDS — each kf feeds BOTH q-halves
    floatx4 s[2][4];
    #pragma unroll
    for (int qh = 0; qh < 2; qh++)
      #pragma unroll
      for (int jk = 0; jk < 4; jk++) s[qh][jk] = floatx4{0.f, 0.f, 0.f, 0.f};
    #pragma unroll
    for (int jk = 0; jk < 4; jk++)
      #pragma unroll
      for (int kc = 0; kc < 2; kc++) {
        short8 kf = *(const short8*)&Ks[cur][(jk * 16 + c) * 72 + kc * 32 + g * 8];
        s[0][jk] = mfma16(qf[0][kc], kf, s[0][jk]);
        s[1][jk] = mfma16(qf[1][kc], kf, s[1][jk]);
      }

    // p = exp2(s); per-lane l; gate by gp; P -> LDS (swizzled C->A transpose)
    #pragma unroll
    for (int qh = 0; qh < 2; qh++)
      #pragma unroll
      for (int jk = 0; jk < 4; jk++) {
        const int colw = (jk << 4) ^ gx16;        // phys col base for this jk
        #pragma unroll
        for (int r = 0; r < 4; r++) {
          const float p = fexp2(s[qh][jk][r]);
          l[qh][r] += p;
          Pw[(qh * 16 + g * 4 + r) * 72 + colw + c] = f2bf(p * gpv[qh][jk][r]);
        }
      }

    // PV: A = P rows (swizzled read), B = V from LDS — each vf feeds both halves
    #pragma unroll
    for (int kc = 0; kc < 2; kc++) {
      short8 af0 = *(const short8*)&Pw[(c) * 72 + kc * 32 + prd * 8];
      short8 af1 = *(const short8*)&Pw[(16 + c) * 72 + kc * 32 + prd * 8];
      #pragma unroll
      for (int jd = 0; jd < 4; jd++) {
        short8 vf = *(const short8*)&Vs[cur][(jd * 16 + c) * 72 + kc * 32 + g * 8];
        o[0][jd] = mfma16(af0, vf, o[0][jd]);
        o[1][jd] = mfma16(af1, vf, o[1][jd]);
      }
    }

    // commit next tile, then barrier
    if (has_next) {
      *(short8*)&Ks[nxt][srow * 72 + scol]      = knx0;
      *(short8*)&Ks[nxt][srow * 72 + scol + 32] = knx1;
      *(short8*)&Vs[nxt][srow * 72 + scol]      = vnx0;
      *(short8*)&Vs[nxt][srow * 72 + scol + 32] = vnx1;
    }
    __syncthreads();
  }

  // l-reduction across the 16 c-lanes (once per kernel), per q-half
  #pragma unroll
  for (int qh = 0; qh < 2; qh++) {
    float invl[4];
    #pragma unroll
    for (int r = 0; r < 4; r++) {
      float rs = l[qh][r];
      rs += __shfl_xor(rs, 1);
      rs += __shfl_xor(rs, 2);
      rs += __shfl_xor(rs, 4);
      rs += __shfl_xor(rs, 8);
      invl[r] = frcp(rs);
    }
    #pragma unroll
    for (int jd = 0; jd < 4; jd++)
      #pragma unroll
      for (int r = 0; r < 4; r++) {
        const int row = qw + qh * 16 + g * 4 + r;
        out[(size_t)(b * NQ_ + row) * 1024 + h * 64 + jd * 16 + c] =
            o[qh][jd][r] * invl[r];
      }
  }
}

extern "C" void kernel_launch(void* const* d_in, const int* in_sizes, int n_in,
                              void* d_out, int out_size, void* d_ws, size_t ws_size,
                              hipStream_t stream) {
  const float* queries = (const float*)d_in[0];
  const float* keys    = (const float*)d_in[1];
  const float* values  = (const float*)d_in[2];
  const float* gp      = (const float*)d_in[3];
  // d_in[4] attention_mask: intentionally unused (reference discards it)
  const float* Wq = (const float*)d_in[5];
  const float* bq = (const float*)d_in[6];
  const float* Wk = (const float*)d_in[7];
  const float* bk = (const float*)d_in[8];
  const float* Wv = (const float*)d_in[9];
  const float* bv = (const float*)d_in[10];

  const size_t SZ_QKV = (size_t)3 * B_ * H_ * NQ_ * DKV_;  // shorts
  const size_t SZ_X   = (size_t)3 * 4096 * 1024;
  const size_t SZ_W   = (size_t)3 * 1024 * 1024;
  const size_t NEED   = (SZ_QKV + SZ_X + SZ_W) * sizeof(ushort_t);

  ushort_t* Qb = (ushort_t*)d_ws;                       // [B,H,NQ,64] bf16, pre-scaled
  ushort_t* Kb = Qb + (size_t)B_ * H_ * NQ_ * DKV_;     // [B,H,NK,64] bf16
  ushort_t* Vt = Kb + (size_t)B_ * H_ * NK_ * DKV_;     // [B,H,64,NK] bf16
  float* out = (float*)d_out;

  if (ws_size >= NEED) {
    ushort_t* Xbf = Qb + SZ_QKV;
    ushort_t* Wt  = Xbf + SZ_X;
    cast_x_kernel<<<dim3(512, 3), 256, 0, stream>>>(queries, keys, values, Xbf);
    cast_wt_kernel<<<dim3(32, 32, 3), 256, 0, stream>>>(Wq, Wk, Wv, Wt);
    proj_kernel2<<<dim3(8, 32, 3), 256, 0, stream>>>(
        Xbf, Wt, bq, bk, bv, Qb, Kb, Vt);
  } else {
    proj_kernel_fb<<<dim3(8, 32, 3), 256, 0, stream>>>(
        queries, keys, values, Wq, Wk, Wv, bq, bk, bv, Qb, Kb, Vt);
  }
  attn_kernel<<<dim3(H_, NQ_ / 128, B_), 256, 0, stream>>>(Qb, Kb, Vt, gp, out);
}

// Round 8
// 245.448 us; speedup vs baseline: 1.8409x; 1.0335x over previous
//
#include <hip/hip_runtime.h>
#include <hip/hip_bf16.h>
#include <cstdint>

typedef unsigned short ushort_t;
typedef __attribute__((ext_vector_type(8))) short short8;
typedef __attribute__((ext_vector_type(4))) float floatx4;
typedef __attribute__((ext_vector_type(4))) unsigned short ushort4_t;

#define H_   16
#define DKV_ 64
#define DM_  1024
#define B_   2
#define NQ_  2048
#define NK_  2048

// fp32 -> bf16 round-to-nearest-even
__device__ __forceinline__ unsigned short f2bf(float f) {
  union { float f; unsigned int u; } v; v.f = f;
  unsigned int u = v.u;
  return (unsigned short)((u + 0x7fffu + ((u >> 16) & 1u)) >> 16);
}

// Trans ops via compiler-visible intrinsics (NOT inline asm) — R5-proven.
__device__ __forceinline__ float fexp2(float x) { return __builtin_amdgcn_exp2f(x); }
__device__ __forceinline__ float frcp(float x)  { return __builtin_amdgcn_rcpf(x); }

__device__ __forceinline__ floatx4 mfma16(short8 a, short8 b, floatx4 c) {
  return __builtin_amdgcn_mfma_f32_16x16x32_bf16(a, b, c, 0, 0, 0);
}

// async global->LDS, 16B per lane; LDS dest = wave-uniform base + lane*16
__device__ __forceinline__ void gload_lds16(const ushort_t* g, ushort_t* l) {
  __builtin_amdgcn_global_load_lds(
      (const __attribute__((address_space(1))) void*)g,
      (__attribute__((address_space(3))) void*)l, 16, 0, 0);
}

// ---------------- cast kernels (R7-proven) --------------------------------
__global__ __launch_bounds__(256) void cast_x_kernel(
    const float* __restrict__ q, const float* __restrict__ k,
    const float* __restrict__ v, ushort_t* __restrict__ dst)
{
  const int t = blockIdx.y;
  const float* src = (t == 0) ? q : (t == 1) ? k : v;
  ushort_t* d = dst + (size_t)t * 4096 * 1024;
  const int gid = blockIdx.x * 256 + threadIdx.x;
  #pragma unroll
  for (int u = 0; u < 8; u++) {
    const int i4 = u * 131072 + gid;
    floatx4 f = ((const floatx4*)src)[i4];
    ushort4_t o;
    #pragma unroll
    for (int e = 0; e < 4; e++) o[e] = f2bf(f[e]);
    *(ushort4_t*)&d[(size_t)i4 * 4] = o;
  }
}

__global__ __launch_bounds__(256) void cast_wt_kernel(
    const float* __restrict__ Wq, const float* __restrict__ Wk,
    const float* __restrict__ Wv, ushort_t* __restrict__ WtAll)
{
  __shared__ ushort_t tile[32][33];
  const int t = blockIdx.z;
  const float* W = (t == 0) ? Wq : (t == 1) ? Wk : Wv;
  ushort_t* Wt = WtAll + (size_t)t * 1024 * 1024;
  const int n0 = blockIdx.x * 32, k0 = blockIdx.y * 32;
  const int tid = threadIdx.x, r = tid >> 3, c4 = (tid & 7) * 4;
  floatx4 f = *(const floatx4*)&W[(size_t)(k0 + r) * 1024 + n0 + c4];
  #pragma unroll
  for (int e = 0; e < 4; e++) tile[r][c4 + e] = f2bf(f[e]);
  __syncthreads();
  ushort4_t o;
  #pragma unroll
  for (int e = 0; e < 4; e++) o[e] = tile[c4 + e][r];
  *(ushort4_t*)&Wt[(size_t)(n0 + r) * 1024 + k0 + c4] = o;
}

// ---------------- proj v3: double-buffered gload_lds (m97 schedule) -------
// R7 analysis: the old loop was SINGLE-buffered (barrier -> gload -> barrier
// -> compute): staging overlapped NOTHING — every K-step serially ate the
// full L2 latency. This is the m90-pattern mistake; m93->m97 (+69%) was
// exactly this fix. v3: two LDS buffers (32KB), ONE barrier per step, loads
// for step t+1 issued before the ds_read/MFMA of step t. Math, fragment
// layout, epilogues byte-identical to the R7-proven version.
__global__ __launch_bounds__(256, 2) void proj_kernel2(
    const ushort_t* __restrict__ Xbf, const ushort_t* __restrict__ WtAll,
    const float* __restrict__ bq, const float* __restrict__ bk,
    const float* __restrict__ bv,
    ushort_t* __restrict__ Qb, ushort_t* __restrict__ Kb, ushort_t* __restrict__ Vt)
{
  const int mode = blockIdx.z;
  const ushort_t* X  = Xbf  + (size_t)mode * 4096 * 1024;
  const ushort_t* Wt = WtAll + (size_t)mode * 1024 * 1024;
  const float* bias  = (mode == 0) ? bq : (mode == 1) ? bk : bv;
  ushort_t* dst      = (mode == 0) ? Qb : (mode == 1) ? Kb : Vt;

  // buf b: SA = SM + b*8192, SB = SM + b*8192 + 4096   (shorts)
  __shared__ ushort_t SM[16384];

  const int tid = threadIdx.x, lane = tid & 63, wid = tid >> 6;
  const int c = lane & 15, g = lane >> 4;
  const int m0 = blockIdx.y * 128, n0 = blockIdx.x * 128;
  const int wm = wid & 1, wn = wid >> 1, mb = wm * 64, nb = wn * 64;
  const int srow = lane >> 2;
  const int schunk = (lane & 3) * 8;

  floatx4 acc[4][4];
  #pragma unroll
  for (int i = 0; i < 4; i++)
    #pragma unroll
    for (int j = 0; j < 4; j++) acc[i][j] = floatx4{0.f, 0.f, 0.f, 0.f};

  // prologue: stage step 0 into buf0
  #pragma unroll
  for (int u = 0; u < 2; u++) {
    const int t = wid * 2 + u;
    gload_lds16(&X [(size_t)(m0 + t * 16 + srow) * 1024 + schunk], &SM[t * 512]);
    gload_lds16(&Wt[(size_t)(n0 + t * 16 + srow) * 1024 + schunk], &SM[4096 + t * 512]);
  }
  __syncthreads();

  for (int step = 0; step < 32; step++) {
    const int cur = step & 1, nxt = cur ^ 1;
    // issue step t+1 staging (lands under this step's compute; the
    // __syncthreads() at the bottom drains it after the MFMAs)
    if (step + 1 < 32) {
      const int k1 = (step + 1) * 32;
      #pragma unroll
      for (int u = 0; u < 2; u++) {
        const int t = wid * 2 + u;
        gload_lds16(&X [(size_t)(m0 + t * 16 + srow) * 1024 + k1 + schunk],
                    &SM[nxt * 8192 + t * 512]);
        gload_lds16(&Wt[(size_t)(n0 + t * 16 + srow) * 1024 + k1 + schunk],
                    &SM[nxt * 8192 + 4096 + t * 512]);
      }
    }
    const ushort_t* SA = &SM[cur * 8192];
    const ushort_t* SB = &SM[cur * 8192 + 4096];
    short8 af[4], bfr[4];
    #pragma unroll
    for (int i = 0; i < 4; i++) af[i]  = *(const short8*)&SA[(mb + i * 16 + c) * 32 + g * 8];
    #pragma unroll
    for (int j = 0; j < 4; j++) bfr[j] = *(const short8*)&SB[(nb + j * 16 + c) * 32 + g * 8];
    #pragma unroll
    for (int i = 0; i < 4; i++)
      #pragma unroll
      for (int j = 0; j < 4; j++) acc[i][j] = mfma16(af[i], bfr[j], acc[i][j]);
    __syncthreads();
  }

  const float scale = (mode == 0) ? 0.18033688011112042f : 1.0f;
  ushort_t* EP = SM + wid * 2048;
  const int hh = (n0 + nb) >> 6;

  if (mode != 2) {
    for (int jj = 0; jj < 2; jj++) {
      #pragma unroll
      for (int jt = 0; jt < 2; jt++) {
        const int j = jj * 2 + jt;
        const float bb = bias[n0 + nb + j * 16 + c];
        #pragma unroll
        for (int i = 0; i < 4; i++)
          #pragma unroll
          for (int r = 0; r < 4; r++)
            EP[(i * 16 + g * 4 + r) * 32 + jt * 16 + c] =
                f2bf((acc[i][j][r] + bb) * scale);
      }
      #pragma unroll
      for (int u = 0; u < 8; u++) {
        const int rowl = u * 8 + (lane >> 3);
        ushort4_t vv = *(ushort4_t*)&EP[rowl * 32 + (lane & 7) * 4];
        const int rowg = m0 + mb + rowl;
        const int bb2 = rowg >> 11, nn = rowg & 2047;
        *(ushort4_t*)&dst[((size_t)(bb2 * H_ + hh) * NQ_ + nn) * DKV_ +
                          jj * 32 + (lane & 7) * 4] = vv;
      }
    }
  } else {
    const int bb2 = (m0 + mb) >> 11, nloc = (m0 + mb) & 2047;
    for (int j = 0; j < 4; j++) {
      const float bb = bias[n0 + nb + j * 16 + c];
      #pragma unroll
      for (int i = 0; i < 4; i++) {
        ushort4_t pk;
        #pragma unroll
        for (int r = 0; r < 4; r++) pk[r] = f2bf(acc[i][j][r] + bb);
        *(ushort4_t*)&EP[c * 72 + i * 16 + g * 4] = pk;
      }
      const int d0 = j * 16;
      #pragma unroll
      for (int u = 0; u < 2; u++) {
        const int coll = u * 8 + (lane >> 3);
        short8 vv = *(const short8*)&EP[coll * 72 + (lane & 7) * 8];
        *(short8*)&dst[((size_t)(bb2 * H_ + hh) * DKV_ + d0 + coll) * NK_ +
                       nloc + (lane & 7) * 8] = vv;
      }
    }
  }
}

// ---------------- proj fallback (R2/R5-proven) ----------------------------
constexpr int LDT = 40;
__global__ __launch_bounds__(256, 2) void proj_kernel_fb(
    const float* __restrict__ Xq, const float* __restrict__ Xk, const float* __restrict__ Xv,
    const float* __restrict__ Wq, const float* __restrict__ Wk, const float* __restrict__ Wv,
    const float* __restrict__ bq, const float* __restrict__ bk, const float* __restrict__ bv,
    ushort_t* __restrict__ Qb, ushort_t* __restrict__ Kb, ushort_t* __restrict__ Vt)
{
  const int mode = blockIdx.z;
  const float* X    = (mode == 0) ? Xq : (mode == 1) ? Xk : Xv;
  const float* W    = (mode == 0) ? Wq : (mode == 1) ? Wk : Wv;
  const float* bias = (mode == 0) ? bq : (mode == 1) ? bk : bv;
  ushort_t* dst     = (mode == 0) ? Qb : (mode == 1) ? Kb : Vt;

  __shared__ ushort_t Asm[128 * LDT];
  __shared__ ushort_t Bsm[128 * LDT];

  const int tid = threadIdx.x, lane = tid & 63, wid = tid >> 6;
  const int m0 = blockIdx.y * 128, n0 = blockIdx.x * 128;
  const int c = lane & 15, g = lane >> 4;
  const int wm = wid & 1, wn = wid >> 1, mb = wm * 64, nb = wn * 64;

  floatx4 acc[4][4];
  #pragma unroll
  for (int i = 0; i < 4; i++)
    #pragma unroll
    for (int j = 0; j < 4; j++) acc[i][j] = floatx4{0.f, 0.f, 0.f, 0.f};

  const int ar = tid >> 1, ah = tid & 1;
  const int bn = tid & 127, bh2 = tid >> 7;

  for (int k0 = 0; k0 < DM_; k0 += 32) {
    const floatx4* ap = (const floatx4*)(X + (size_t)(m0 + ar) * DM_ + k0 + ah * 16);
    floatx4 av0 = ap[0], av1 = ap[1], av2 = ap[2], av3 = ap[3];
    const float* wp = W + (size_t)(k0 + bh2 * 16) * 1024 + n0 + bn;
    float wv[16];
    #pragma unroll
    for (int j = 0; j < 16; j++) wv[j] = wp[j * 1024];
    short8 pa0, pa1, pb0, pb1;
    #pragma unroll
    for (int j = 0; j < 4; j++) {
      pa0[j] = (short)f2bf(av0[j]); pa0[4 + j] = (short)f2bf(av1[j]);
      pa1[j] = (short)f2bf(av2[j]); pa1[4 + j] = (short)f2bf(av3[j]);
    }
    #pragma unroll
    for (int j = 0; j < 8; j++) { pb0[j] = (short)f2bf(wv[j]); pb1[j] = (short)f2bf(wv[8 + j]); }
    __syncthreads();
    *(short8*)&Asm[ar * LDT + ah * 16]      = pa0;
    *(short8*)&Asm[ar * LDT + ah * 16 + 8]  = pa1;
    *(short8*)&Bsm[bn * LDT + bh2 * 16]     = pb0;
    *(short8*)&Bsm[bn * LDT + bh2 * 16 + 8] = pb1;
    __syncthreads();
    short8 af[4], bfr[4];
    #pragma unroll
    for (int i = 0; i < 4; i++) af[i]  = *(const short8*)&Asm[(mb + i * 16 + c) * LDT + g * 8];
    #pragma unroll
    for (int j = 0; j < 4; j++) bfr[j] = *(const short8*)&Bsm[(nb + j * 16 + c) * LDT + g * 8];
    #pragma unroll
    for (int i = 0; i < 4; i++)
      #pragma unroll
      for (int j = 0; j < 4; j++) acc[i][j] = mfma16(af[i], bfr[j], acc[i][j]);
  }
  #pragma unroll
  for (int j = 0; j < 4; j++) {
    const int col = n0 + nb + j * 16 + c;
    const float bv_ = bias[col];
    const int h = col >> 6, d = col & 63;
    #pragma unroll
    for (int i = 0; i < 4; i++)
      #pragma unroll
      for (int r = 0; r < 4; r++) {
        const int row = m0 + mb + i * 16 + g * 4 + r;
        const int b = row >> 11, n = row & 2047;
        float v = acc[i][j][r] + bv_;
        if (mode == 0) {
          v *= 0.18033688011112042f;
          dst[((size_t)(b * H_ + h) * NQ_ + n) * DKV_ + d] = f2bf(v);
        } else if (mode == 1) {
          dst[((size_t)(b * H_ + h) * NQ_ + n) * DKV_ + d] = f2bf(v);
        } else {
          dst[((size_t)(b * H_ + h) * DKV_ + d) * NK_ + n] = f2bf(v);
        }
      }
  }
}

// ---------------- attn v4 (R0-proven best: 86.9us) — reverted verbatim ----
// R7 scoreboard: every attn restructure (v5-v11: lean body, pipeline,
// counted-wait, split-k, XCD swizzles, no-LDS, 32q/wave) landed 93-299us.
// v4's balance of LDS work / VALU filler / 4 waves-per-SIMD latency hiding
// is the empirical optimum; declared converged for now.
__global__ __launch_bounds__(512, 4) void attn_kernel(
    const ushort_t* __restrict__ Qb, const ushort_t* __restrict__ Kb,
    const ushort_t* __restrict__ Vt, const float* __restrict__ gp,
    float* __restrict__ out)
{
  __shared__ ushort_t Ks[2][64 * 72];
  __shared__ ushort_t Vs[2][64 * 72];
  __shared__ ushort_t Pl[8][16 * 72];

  const int tid = threadIdx.x, lane = tid & 63, wid = tid >> 6;  // wid 0..7
  const int c = lane & 15, g = lane >> 4;
  const int h = blockIdx.x, b = blockIdx.z;       // h fastest: gp L2 locality
  const int bh = b * H_ + h;
  const int qw = blockIdx.y * 128 + wid * 16;

  const ushort_t* Qp = Qb + (size_t)bh * NQ_ * DKV_;
  const ushort_t* Kp = Kb + (size_t)bh * NK_ * DKV_;
  const ushort_t* Vp = Vt + (size_t)bh * DKV_ * NK_;
  const float* gpp = gp + (size_t)b * NQ_ * NK_ + (size_t)qw * NK_;
  ushort_t* Pw = Pl[wid];

  const int gx16 = (g >> 1) << 4;                 // write-side granule XOR
  const int prd  = g ^ (((c >> 3) & 1) << 1);     // read-side swizzled g

  // cooperative staging: 512 threads cover 64x64, 1 chunk each for K and V
  const int srow = tid >> 3;                      // 0..63
  const int scol = (tid & 7) * 8;                 // 0..56

  // Q fragments resident (pre-scaled by log2(e)/8)
  short8 qf[2];
  #pragma unroll
  for (int kc = 0; kc < 2; kc++)
    qf[kc] = *(const short8*)&Qp[(qw + c) * DKV_ + kc * 32 + g * 8];

  // stage tile 0
  *(short8*)&Ks[0][srow * 72 + scol] = *(const short8*)&Kp[(size_t)srow * DKV_ + scol];
  *(short8*)&Vs[0][srow * 72 + scol] = *(const short8*)&Vp[(size_t)srow * NK_ + scol];
  __syncthreads();

  floatx4 o[4];
  float l[4];
  #pragma unroll
  for (int jd = 0; jd < 4; jd++) o[jd] = floatx4{0.f, 0.f, 0.f, 0.f};
  #pragma unroll
  for (int r = 0; r < 4; r++) l[r] = 0.f;

  for (int t = 0; t < NK_ / 64; t++) {
    const int k0 = t * 64;
    const int cur = t & 1, nxt = cur ^ 1;

    // gp gathers first (consumed after S-MFMA)
    float gpv[4][4];
    #pragma unroll
    for (int r = 0; r < 4; r++) {
      const float* gq = gpp + (size_t)(g * 4 + r) * NK_ + k0 + c;
      #pragma unroll
      for (int jk = 0; jk < 4; jk++) gpv[jk][r] = gq[jk * 16];
    }

    // issue next tile's staging loads (latency covered by whole body)
    short8 knx, vnx;
    const bool has_next = (t + 1) < NK_ / 64;
    if (has_next) {
      const int k1 = k0 + 64;
      knx = *(const short8*)&Kp[(size_t)(k1 + srow) * DKV_ + scol];
      vnx = *(const short8*)&Vp[(size_t)srow * NK_ + k1 + scol];
    }

    // S = Q K^T (log2 domain), K from LDS
    floatx4 s[4];
    #pragma unroll
    for (int jk = 0; jk < 4; jk++) s[jk] = floatx4{0.f, 0.f, 0.f, 0.f};
    #pragma unroll
    for (int jk = 0; jk < 4; jk++)
      #pragma unroll
      for (int kc = 0; kc < 2; kc++) {
        short8 kf = *(const short8*)&Ks[cur][(jk * 16 + c) * 72 + kc * 32 + g * 8];
        s[jk] = mfma16(qf[kc], kf, s[jk]);
      }

    // p = exp2(s); per-lane l; gate by gp; P -> LDS (swizzled C->A transpose)
    #pragma unroll
    for (int jk = 0; jk < 4; jk++) {
      const int colw = (jk << 4) ^ gx16;          // phys col base for this jk
      #pragma unroll
      for (int r = 0; r < 4; r++) {
        const float p = fexp2(s[jk][r]);
        l[r] += p;
        Pw[(g * 4 + r) * 72 + colw + c] = f2bf(p * gpv[jk][r]);
      }
    }

    // PV: A = P rows (swizzled read), B = V from LDS
    #pragma unroll
    for (int kc = 0; kc < 2; kc++) {
      short8 af = *(const short8*)&Pw[c * 72 + kc * 32 + prd * 8];
      #pragma unroll
      for (int jd = 0; jd < 4; jd++) {
        short8 vf = *(const short8*)&Vs[cur][(jd * 16 + c) * 72 + kc * 32 + g * 8];
        o[jd] = mfma16(af, vf, o[jd]);
      }
    }

    // commit next tile, then barrier
    if (has_next) {
      *(short8*)&Ks[nxt][srow * 72 + scol] = knx;
      *(short8*)&Vs[nxt][srow * 72 + scol] = vnx;
    }
    __syncthreads();
  }

  // l-reduction across the 16 c-lanes (once per kernel)
  float invl[4];
  #pragma unroll
  for (int r = 0; r < 4; r++) {
    float rs = l[r];
    rs += __shfl_xor(rs, 1);
    rs += __shfl_xor(rs, 2);
    rs += __shfl_xor(rs, 4);
    rs += __shfl_xor(rs, 8);
    invl[r] = frcp(rs);
  }
  #pragma unroll
  for (int jd = 0; jd < 4; jd++)
    #pragma unroll
    for (int r = 0; r < 4; r++) {
      const int row = qw + g * 4 + r;
      out[(size_t)(b * NQ_ + row) * 1024 + h * 64 + jd * 16 + c] =
          o[jd][r] * invl[r];
    }
}

extern "C" void kernel_launch(void* const* d_in, const int* in_sizes, int n_in,
                              void* d_out, int out_size, void* d_ws, size_t ws_size,
                              hipStream_t stream) {
  const float* queries = (const float*)d_in[0];
  const float* keys    = (const float*)d_in[1];
  const float* values  = (const float*)d_in[2];
  const float* gp      = (const float*)d_in[3];
  // d_in[4] attention_mask: intentionally unused (reference discards it)
  const float* Wq = (const float*)d_in[5];
  const float* bq = (const float*)d_in[6];
  const float* Wk = (const float*)d_in[7];
  const float* bk = (const float*)d_in[8];
  const float* Wv = (const float*)d_in[9];
  const float* bv = (const float*)d_in[10];

  const size_t SZ_QKV = (size_t)3 * B_ * H_ * NQ_ * DKV_;  // shorts
  const size_t SZ_X   = (size_t)3 * 4096 * 1024;
  const size_t SZ_W   = (size_t)3 * 1024 * 1024;
  const size_t NEED   = (SZ_QKV + SZ_X + SZ_W) * sizeof(ushort_t);

  ushort_t* Qb = (ushort_t*)d_ws;                       // [B,H,NQ,64] bf16, pre-scaled
  ushort_t* Kb = Qb + (size_t)B_ * H_ * NQ_ * DKV_;     // [B,H,NK,64] bf16
  ushort_t* Vt = Kb + (size_t)B_ * H_ * NK_ * DKV_;     // [B,H,64,NK] bf16
  float* out = (float*)d_out;

  if (ws_size >= NEED) {
    ushort_t* Xbf = Qb + SZ_QKV;
    ushort_t* Wt  = Xbf + SZ_X;
    cast_x_kernel<<<dim3(512, 3), 256, 0, stream>>>(queries, keys, values, Xbf);
    cast_wt_kernel<<<dim3(32, 32, 3), 256, 0, stream>>>(Wq, Wk, Wv, Wt);
    proj_kernel2<<<dim3(8, 32, 3), 256, 0, stream>>>(
        Xbf, Wt, bq, bk, bv, Qb, Kb, Vt);
  } else {
    proj_kernel_fb<<<dim3(8, 32, 3), 256, 0, stream>>>(
        queries, keys, values, Wq, Wk, Wv, bq, bk, bv, Qb, Kb, Vt);
  }
  attn_kernel<<<dim3(H_, NQ_ / 128, B_), 512, 0, stream>>>(Qb, Kb, Vt, gp, out);
}

// Round 9
// 244.404 us; speedup vs baseline: 1.8488x; 1.0043x over previous
//
#include <hip/hip_runtime.h>
#include <hip/hip_bf16.h>
#include <cstdint>

typedef unsigned short ushort_t;
typedef __attribute__((ext_vector_type(8))) short short8;
typedef __attribute__((ext_vector_type(4))) float floatx4;
typedef __attribute__((ext_vector_type(4))) unsigned short ushort4_t;

#define H_   16
#define DKV_ 64
#define DM_  1024
#define B_   2
#define NQ_  2048
#define NK_  2048

// fp32 -> bf16 round-to-nearest-even
__device__ __forceinline__ unsigned short f2bf(float f) {
  union { float f; unsigned int u; } v; v.f = f;
  unsigned int u = v.u;
  return (unsigned short)((u + 0x7fffu + ((u >> 16) & 1u)) >> 16);
}

// Trans ops via compiler-visible intrinsics (NOT inline asm) — R5-proven.
__device__ __forceinline__ float fexp2(float x) { return __builtin_amdgcn_exp2f(x); }
__device__ __forceinline__ float frcp(float x)  { return __builtin_amdgcn_rcpf(x); }

__device__ __forceinline__ floatx4 mfma16(short8 a, short8 b, floatx4 c) {
  return __builtin_amdgcn_mfma_f32_16x16x32_bf16(a, b, c, 0, 0, 0);
}

// async global->LDS, 16B per lane; LDS dest = wave-uniform base + lane*16
__device__ __forceinline__ void gload_lds16(const ushort_t* g, ushort_t* l) {
  __builtin_amdgcn_global_load_lds(
      (const __attribute__((address_space(1))) void*)g,
      (__attribute__((address_space(3))) void*)l, 16, 0, 0);
}

// lgkm-only barrier (R3-proven): drains LDS ops but NOT vmem, so prefetch
// global loads stay in flight across tiles. __syncthreads() would emit
// s_waitcnt vmcnt(0) and drain the gp prefetch every tile.
__device__ __forceinline__ void block_sync_lds() {
  asm volatile("s_waitcnt lgkmcnt(0)" ::: "memory");
  __builtin_amdgcn_s_barrier();
  __builtin_amdgcn_sched_barrier(0);
}

// ---------------- cast kernels (R7-proven) --------------------------------
__global__ __launch_bounds__(256) void cast_x_kernel(
    const float* __restrict__ q, const float* __restrict__ k,
    const float* __restrict__ v, ushort_t* __restrict__ dst)
{
  const int t = blockIdx.y;
  const float* src = (t == 0) ? q : (t == 1) ? k : v;
  ushort_t* d = dst + (size_t)t * 4096 * 1024;
  const int gid = blockIdx.x * 256 + threadIdx.x;
  #pragma unroll
  for (int u = 0; u < 8; u++) {
    const int i4 = u * 131072 + gid;
    floatx4 f = ((const floatx4*)src)[i4];
    ushort4_t o;
    #pragma unroll
    for (int e = 0; e < 4; e++) o[e] = f2bf(f[e]);
    *(ushort4_t*)&d[(size_t)i4 * 4] = o;
  }
}

__global__ __launch_bounds__(256) void cast_wt_kernel(
    const float* __restrict__ Wq, const float* __restrict__ Wk,
    const float* __restrict__ Wv, ushort_t* __restrict__ WtAll)
{
  __shared__ ushort_t tile[32][33];
  const int t = blockIdx.z;
  const float* W = (t == 0) ? Wq : (t == 1) ? Wk : Wv;
  ushort_t* Wt = WtAll + (size_t)t * 1024 * 1024;
  const int n0 = blockIdx.x * 32, k0 = blockIdx.y * 32;
  const int tid = threadIdx.x, r = tid >> 3, c4 = (tid & 7) * 4;
  floatx4 f = *(const floatx4*)&W[(size_t)(k0 + r) * 1024 + n0 + c4];
  #pragma unroll
  for (int e = 0; e < 4; e++) tile[r][c4 + e] = f2bf(f[e]);
  __syncthreads();
  ushort4_t o;
  #pragma unroll
  for (int e = 0; e < 4; e++) o[e] = tile[c4 + e][r];
  *(ushort4_t*)&Wt[(size_t)(n0 + r) * 1024 + k0 + c4] = o;
}

// ---------------- proj v3: double-buffered gload_lds (R8, kept) -----------
__global__ __launch_bounds__(256, 2) void proj_kernel2(
    const ushort_t* __restrict__ Xbf, const ushort_t* __restrict__ WtAll,
    const float* __restrict__ bq, const float* __restrict__ bk,
    const float* __restrict__ bv,
    ushort_t* __restrict__ Qb, ushort_t* __restrict__ Kb, ushort_t* __restrict__ Vt)
{
  const int mode = blockIdx.z;
  const ushort_t* X  = Xbf  + (size_t)mode * 4096 * 1024;
  const ushort_t* Wt = WtAll + (size_t)mode * 1024 * 1024;
  const float* bias  = (mode == 0) ? bq : (mode == 1) ? bk : bv;
  ushort_t* dst      = (mode == 0) ? Qb : (mode == 1) ? Kb : Vt;

  // buf b: SA = SM + b*8192, SB = SM + b*8192 + 4096   (shorts)
  __shared__ ushort_t SM[16384];

  const int tid = threadIdx.x, lane = tid & 63, wid = tid >> 6;
  const int c = lane & 15, g = lane >> 4;
  const int m0 = blockIdx.y * 128, n0 = blockIdx.x * 128;
  const int wm = wid & 1, wn = wid >> 1, mb = wm * 64, nb = wn * 64;
  const int srow = lane >> 2;
  const int schunk = (lane & 3) * 8;

  floatx4 acc[4][4];
  #pragma unroll
  for (int i = 0; i < 4; i++)
    #pragma unroll
    for (int j = 0; j < 4; j++) acc[i][j] = floatx4{0.f, 0.f, 0.f, 0.f};

  // prologue: stage step 0 into buf0
  #pragma unroll
  for (int u = 0; u < 2; u++) {
    const int t = wid * 2 + u;
    gload_lds16(&X [(size_t)(m0 + t * 16 + srow) * 1024 + schunk], &SM[t * 512]);
    gload_lds16(&Wt[(size_t)(n0 + t * 16 + srow) * 1024 + schunk], &SM[4096 + t * 512]);
  }
  __syncthreads();

  for (int step = 0; step < 32; step++) {
    const int cur = step & 1, nxt = cur ^ 1;
    if (step + 1 < 32) {
      const int k1 = (step + 1) * 32;
      #pragma unroll
      for (int u = 0; u < 2; u++) {
        const int t = wid * 2 + u;
        gload_lds16(&X [(size_t)(m0 + t * 16 + srow) * 1024 + k1 + schunk],
                    &SM[nxt * 8192 + t * 512]);
        gload_lds16(&Wt[(size_t)(n0 + t * 16 + srow) * 1024 + k1 + schunk],
                    &SM[nxt * 8192 + 4096 + t * 512]);
      }
    }
    const ushort_t* SA = &SM[cur * 8192];
    const ushort_t* SB = &SM[cur * 8192 + 4096];
    short8 af[4], bfr[4];
    #pragma unroll
    for (int i = 0; i < 4; i++) af[i]  = *(const short8*)&SA[(mb + i * 16 + c) * 32 + g * 8];
    #pragma unroll
    for (int j = 0; j < 4; j++) bfr[j] = *(const short8*)&SB[(nb + j * 16 + c) * 32 + g * 8];
    #pragma unroll
    for (int i = 0; i < 4; i++)
      #pragma unroll
      for (int j = 0; j < 4; j++) acc[i][j] = mfma16(af[i], bfr[j], acc[i][j]);
    __syncthreads();
  }

  const float scale = (mode == 0) ? 0.18033688011112042f : 1.0f;
  ushort_t* EP = SM + wid * 2048;
  const int hh = (n0 + nb) >> 6;

  if (mode != 2) {
    for (int jj = 0; jj < 2; jj++) {
      #pragma unroll
      for (int jt = 0; jt < 2; jt++) {
        const int j = jj * 2 + jt;
        const float bb = bias[n0 + nb + j * 16 + c];
        #pragma unroll
        for (int i = 0; i < 4; i++)
          #pragma unroll
          for (int r = 0; r < 4; r++)
            EP[(i * 16 + g * 4 + r) * 32 + jt * 16 + c] =
                f2bf((acc[i][j][r] + bb) * scale);
      }
      #pragma unroll
      for (int u = 0; u < 8; u++) {
        const int rowl = u * 8 + (lane >> 3);
        ushort4_t vv = *(ushort4_t*)&EP[rowl * 32 + (lane & 7) * 4];
        const int rowg = m0 + mb + rowl;
        const int bb2 = rowg >> 11, nn = rowg & 2047;
        *(ushort4_t*)&dst[((size_t)(bb2 * H_ + hh) * NQ_ + nn) * DKV_ +
                          jj * 32 + (lane & 7) * 4] = vv;
      }
    }
  } else {
    const int bb2 = (m0 + mb) >> 11, nloc = (m0 + mb) & 2047;
    for (int j = 0; j < 4; j++) {
      const float bb = bias[n0 + nb + j * 16 + c];
      #pragma unroll
      for (int i = 0; i < 4; i++) {
        ushort4_t pk;
        #pragma unroll
        for (int r = 0; r < 4; r++) pk[r] = f2bf(acc[i][j][r] + bb);
        *(ushort4_t*)&EP[c * 72 + i * 16 + g * 4] = pk;
      }
      const int d0 = j * 16;
      #pragma unroll
      for (int u = 0; u < 2; u++) {
        const int coll = u * 8 + (lane >> 3);
        short8 vv = *(const short8*)&EP[coll * 72 + (lane & 7) * 8];
        *(short8*)&dst[((size_t)(bb2 * H_ + hh) * DKV_ + d0 + coll) * NK_ +
                       nloc + (lane & 7) * 8] = vv;
      }
    }
  }
}

// ---------------- proj fallback (R2/R5-proven) ----------------------------
constexpr int LDT = 40;
__global__ __launch_bounds__(256, 2) void proj_kernel_fb(
    const float* __restrict__ Xq, const float* __restrict__ Xk, const float* __restrict__ Xv,
    const float* __restrict__ Wq, const float* __restrict__ Wk, const float* __restrict__ Wv,
    const float* __restrict__ bq, const float* __restrict__ bk, const float* __restrict__ bv,
    ushort_t* __restrict__ Qb, ushort_t* __restrict__ Kb, ushort_t* __restrict__ Vt)
{
  const int mode = blockIdx.z;
  const float* X    = (mode == 0) ? Xq : (mode == 1) ? Xk : Xv;
  const float* W    = (mode == 0) ? Wq : (mode == 1) ? Wk : Wv;
  const float* bias = (mode == 0) ? bq : (mode == 1) ? bk : bv;
  ushort_t* dst     = (mode == 0) ? Qb : (mode == 1) ? Kb : Vt;

  __shared__ ushort_t Asm[128 * LDT];
  __shared__ ushort_t Bsm[128 * LDT];

  const int tid = threadIdx.x, lane = tid & 63, wid = tid >> 6;
  const int m0 = blockIdx.y * 128, n0 = blockIdx.x * 128;
  const int c = lane & 15, g = lane >> 4;
  const int wm = wid & 1, wn = wid >> 1, mb = wm * 64, nb = wn * 64;

  floatx4 acc[4][4];
  #pragma unroll
  for (int i = 0; i < 4; i++)
    #pragma unroll
    for (int j = 0; j < 4; j++) acc[i][j] = floatx4{0.f, 0.f, 0.f, 0.f};

  const int ar = tid >> 1, ah = tid & 1;
  const int bn = tid & 127, bh2 = tid >> 7;

  for (int k0 = 0; k0 < DM_; k0 += 32) {
    const floatx4* ap = (const floatx4*)(X + (size_t)(m0 + ar) * DM_ + k0 + ah * 16);
    floatx4 av0 = ap[0], av1 = ap[1], av2 = ap[2], av3 = ap[3];
    const float* wp = W + (size_t)(k0 + bh2 * 16) * 1024 + n0 + bn;
    float wv[16];
    #pragma unroll
    for (int j = 0; j < 16; j++) wv[j] = wp[j * 1024];
    short8 pa0, pa1, pb0, pb1;
    #pragma unroll
    for (int j = 0; j < 4; j++) {
      pa0[j] = (short)f2bf(av0[j]); pa0[4 + j] = (short)f2bf(av1[j]);
      pa1[j] = (short)f2bf(av2[j]); pa1[4 + j] = (short)f2bf(av3[j]);
    }
    #pragma unroll
    for (int j = 0; j < 8; j++) { pb0[j] = (short)f2bf(wv[j]); pb1[j] = (short)f2bf(wv[8 + j]); }
    __syncthreads();
    *(short8*)&Asm[ar * LDT + ah * 16]      = pa0;
    *(short8*)&Asm[ar * LDT + ah * 16 + 8]  = pa1;
    *(short8*)&Bsm[bn * LDT + bh2 * 16]     = pb0;
    *(short8*)&Bsm[bn * LDT + bh2 * 16 + 8] = pb1;
    __syncthreads();
    short8 af[4], bfr[4];
    #pragma unroll
    for (int i = 0; i < 4; i++) af[i]  = *(const short8*)&Asm[(mb + i * 16 + c) * LDT + g * 8];
    #pragma unroll
    for (int j = 0; j < 4; j++) bfr[j] = *(const short8*)&Bsm[(nb + j * 16 + c) * LDT + g * 8];
    #pragma unroll
    for (int i = 0; i < 4; i++)
      #pragma unroll
      for (int j = 0; j < 4; j++) acc[i][j] = mfma16(af[i], bfr[j], acc[i][j]);
  }
  #pragma unroll
  for (int j = 0; j < 4; j++) {
    const int col = n0 + nb + j * 16 + c;
    const float bv_ = bias[col];
    const int h = col >> 6, d = col & 63;
    #pragma unroll
    for (int i = 0; i < 4; i++)
      #pragma unroll
      for (int r = 0; r < 4; r++) {
        const int row = m0 + mb + i * 16 + g * 4 + r;
        const int b = row >> 11, n = row & 2047;
        float v = acc[i][j][r] + bv_;
        if (mode == 0) {
          v *= 0.18033688011112042f;
          dst[((size_t)(b * H_ + h) * NQ_ + n) * DKV_ + d] = f2bf(v);
        } else if (mode == 1) {
          dst[((size_t)(b * H_ + h) * NQ_ + n) * DKV_ + d] = f2bf(v);
        } else {
          dst[((size_t)(b * H_ + h) * DKV_ + d) * NK_ + n] = f2bf(v);
        }
      }
  }
}

// ---------------- attn v12: v4 body + gp ping-pong + lgkm-only barrier ----
// R8 audit: v11 (30% less LDS-pipe work) was SLOWER than v4 => v4 is a
// latency/ILP equilibrium, not LDS-throughput-bound. The one untested
// isolated lever on v4: its gp gather is issued AND consumed within the
// same tile (cover ~250cy < L3 latency ~500-700cy), and __syncthreads'
// vmcnt(0) would drain any prefetch. v12 = v4 byte-identical math with:
//   (a) gp(t+1) loaded into ping-pong regs (issued AFTER the K/V stage
//       loads => younger in vmem queue; commit's auto-counted wait on the
//       stage regs leaves gp in flight),
//   (b) per-tile barrier = lgkmcnt(0)+s_barrier (R3-proven protocol: all
//       cross-wave hazards are LDS; vmem ordered by register deps).
// Single-variable A/B on the champion. VGPR +16 (~76) — 16 waves/CU kept.
__global__ __launch_bounds__(512, 4) void attn_kernel(
    const ushort_t* __restrict__ Qb, const ushort_t* __restrict__ Kb,
    const ushort_t* __restrict__ Vt, const float* __restrict__ gp,
    float* __restrict__ out)
{
  __shared__ ushort_t Ks[2][64 * 72];
  __shared__ ushort_t Vs[2][64 * 72];
  __shared__ ushort_t Pl[8][16 * 72];

  constexpr int NT = NK_ / 64;                    // 32 tiles

  const int tid = threadIdx.x, lane = tid & 63, wid = tid >> 6;  // wid 0..7
  const int c = lane & 15, g = lane >> 4;
  const int h = blockIdx.x, b = blockIdx.z;       // h fastest: gp L2 locality
  const int bh = b * H_ + h;
  const int qw = blockIdx.y * 128 + wid * 16;

  const ushort_t* Qp = Qb + (size_t)bh * NQ_ * DKV_;
  const ushort_t* Kp = Kb + (size_t)bh * NK_ * DKV_;
  const ushort_t* Vp = Vt + (size_t)bh * DKV_ * NK_;
  const float* gpp = gp + (size_t)b * NQ_ * NK_ + (size_t)qw * NK_;
  ushort_t* Pw = Pl[wid];

  const int gx16 = (g >> 1) << 4;                 // write-side granule XOR
  const int prd  = g ^ (((c >> 3) & 1) << 1);     // read-side swizzled g

  // cooperative staging: 512 threads cover 64x64, 1 chunk each for K and V
  const int srow = tid >> 3;                      // 0..63
  const int scol = (tid & 7) * 8;                 // 0..56

  // Q fragments resident (pre-scaled by log2(e)/8)
  short8 qf[2];
  #pragma unroll
  for (int kc = 0; kc < 2; kc++)
    qf[kc] = *(const short8*)&Qp[(qw + c) * DKV_ + kc * 32 + g * 8];

  // stage tile 0; gp(0) into gpA
  *(short8*)&Ks[0][srow * 72 + scol] = *(const short8*)&Kp[(size_t)srow * DKV_ + scol];
  *(short8*)&Vs[0][srow * 72 + scol] = *(const short8*)&Vp[(size_t)srow * NK_ + scol];
  float gpA[4][4], gpB[4][4];
  #pragma unroll
  for (int r = 0; r < 4; r++) {
    const float* gq = gpp + (size_t)(g * 4 + r) * NK_ + c;
    #pragma unroll
    for (int jk = 0; jk < 4; jk++) gpA[jk][r] = gq[jk * 16];
  }
  __syncthreads();   // one-time full drain

  floatx4 o[4];
  float l[4];
  #pragma unroll
  for (int jd = 0; jd < 4; jd++) o[jd] = floatx4{0.f, 0.f, 0.f, 0.f};
  #pragma unroll
  for (int r = 0; r < 4; r++) l[r] = 0.f;

  // body: compute tile T from LDS[CUR], gate with GPC (loaded last tile);
  // issue stage(T+1) then gp(T+1)->GPN; commit stage; lgkm-only barrier.
#define ATTN_BODY(T, CUR, GPC, GPN)                                          \
  {                                                                          \
    const int t_ = (T);                                                      \
    const int k0 = t_ * 64;                                                  \
    const bool hn = (t_ + 1) < NT;                                           \
    /* stage loads FIRST (older in vmem queue than gp) */                    \
    short8 knx, vnx;                                                         \
    if (hn) {                                                                \
      const int k1 = k0 + 64;                                                \
      knx = *(const short8*)&Kp[(size_t)(k1 + srow) * DKV_ + scol];          \
      vnx = *(const short8*)&Vp[(size_t)srow * NK_ + k1 + scol];             \
    }                                                                        \
    /* gp(t+1) into GPN (consumed next tile; survives the lgkm barrier) */   \
    if (hn) {                                                                \
      const int k1 = k0 + 64;                                                \
      _Pragma("unroll")                                                      \
      for (int r = 0; r < 4; r++) {                                          \
        const float* gq = gpp + (size_t)(g * 4 + r) * NK_ + k1 + c;          \
        _Pragma("unroll")                                                    \
        for (int jk = 0; jk < 4; jk++) GPN[jk][r] = gq[jk * 16];             \
      }                                                                      \
    }                                                                        \
    /* S = Q K^T (log2 domain), K from LDS */                                \
    floatx4 s_[4];                                                           \
    _Pragma("unroll")                                                        \
    for (int jk = 0; jk < 4; jk++) s_[jk] = floatx4{0.f, 0.f, 0.f, 0.f};     \
    _Pragma("unroll")                                                        \
    for (int jk = 0; jk < 4; jk++)                                           \
      _Pragma("unroll")                                                      \
      for (int kc = 0; kc < 2; kc++) {                                       \
        short8 kf = *(const short8*)&Ks[CUR][(jk * 16 + c) * 72 + kc * 32 + g * 8]; \
        s_[jk] = mfma16(qf[kc], kf, s_[jk]);                                 \
      }                                                                      \
    /* p = exp2(s); per-lane l; gate by GPC; P -> LDS (swizzled) */          \
    _Pragma("unroll")                                                        \
    for (int jk = 0; jk < 4; jk++) {                                         \
      const int colw = (jk << 4) ^ gx16;                                     \
      _Pragma("unroll")                                                      \
      for (int r = 0; r < 4; r++) {                                          \
        const float p = fexp2(s_[jk][r]);                                    \
        l[r] += p;                                                           \
        Pw[(g * 4 + r) * 72 + colw + c] = f2bf(p * GPC[jk][r]);              \
      }                                                                      \
    }                                                                        \
    /* PV: A = P rows (swizzled read), B = V from LDS */                     \
    _Pragma("unroll")                                                        \
    for (int kc = 0; kc < 2; kc++) {                                         \
      short8 af = *(const short8*)&Pw[c * 72 + kc * 32 + prd * 8];           \
      _Pragma("unroll")                                                      \
      for (int jd = 0; jd < 4; jd++) {                                       \
        short8 vf = *(const short8*)&Vs[CUR][(jd * 16 + c) * 72 + kc * 32 + g * 8]; \
        o[jd] = mfma16(af, vf, o[jd]);                                       \
      }                                                                      \
    }                                                                        \
    /* commit tile t+1 (vmcnt auto-counted on knx/vnx; gp stays in flight)*/ \
    if (hn) {                                                                \
      *(short8*)&Ks[(CUR) ^ 1][srow * 72 + scol] = knx;                      \
      *(short8*)&Vs[(CUR) ^ 1][srow * 72 + scol] = vnx;                      \
    }                                                                        \
    block_sync_lds();                                                        \
  }

  for (int tt = 0; tt < NT; tt += 2) {
    ATTN_BODY(tt,     0, gpA, gpB)
    ATTN_BODY(tt + 1, 1, gpB, gpA)
  }
#undef ATTN_BODY

  // l-reduction across the 16 c-lanes (once per kernel)
  float invl[4];
  #pragma unroll
  for (int r = 0; r < 4; r++) {
    float rs = l[r];
    rs += __shfl_xor(rs, 1);
    rs += __shfl_xor(rs, 2);
    rs += __shfl_xor(rs, 4);
    rs += __shfl_xor(rs, 8);
    invl[r] = frcp(rs);
  }
  #pragma unroll
  for (int jd = 0; jd < 4; jd++)
    #pragma unroll
    for (int r = 0; r < 4; r++) {
      const int row = qw + g * 4 + r;
      out[(size_t)(b * NQ_ + row) * 1024 + h * 64 + jd * 16 + c] =
          o[jd][r] * invl[r];
    }
}

extern "C" void kernel_launch(void* const* d_in, const int* in_sizes, int n_in,
                              void* d_out, int out_size, void* d_ws, size_t ws_size,
                              hipStream_t stream) {
  const float* queries = (const float*)d_in[0];
  const float* keys    = (const float*)d_in[1];
  const float* values  = (const float*)d_in[2];
  const float* gp      = (const float*)d_in[3];
  // d_in[4] attention_mask: intentionally unused (reference discards it)
  const float* Wq = (const float*)d_in[5];
  const float* bq = (const float*)d_in[6];
  const float* Wk = (const float*)d_in[7];
  const float* bk = (const float*)d_in[8];
  const float* Wv = (const float*)d_in[9];
  const float* bv = (const float*)d_in[10];

  const size_t SZ_QKV = (size_t)3 * B_ * H_ * NQ_ * DKV_;  // shorts
  const size_t SZ_X   = (size_t)3 * 4096 * 1024;
  const size_t SZ_W   = (size_t)3 * 1024 * 1024;
  const size_t NEED   = (SZ_QKV + SZ_X + SZ_W) * sizeof(ushort_t);

  ushort_t* Qb = (ushort_t*)d_ws;                       // [B,H,NQ,64] bf16, pre-scaled
  ushort_t* Kb = Qb + (size_t)B_ * H_ * NQ_ * DKV_;     // [B,H,NK,64] bf16
  ushort_t* Vt = Kb + (size_t)B_ * H_ * NK_ * DKV_;     // [B,H,64,NK] bf16
  float* out = (float*)d_out;

  if (ws_size >= NEED) {
    ushort_t* Xbf = Qb + SZ_QKV;
    ushort_t* Wt  = Xbf + SZ_X;
    cast_x_kernel<<<dim3(512, 3), 256, 0, stream>>>(queries, keys, values, Xbf);
    cast_wt_kernel<<<dim3(32, 32, 3), 256, 0, stream>>>(Wq, Wk, Wv, Wt);
    proj_kernel2<<<dim3(8, 32, 3), 256, 0, stream>>>(
        Xbf, Wt, bq, bk, bv, Qb, Kb, Vt);
  } else {
    proj_kernel_fb<<<dim3(8, 32, 3), 256, 0, stream>>>(
        queries, keys, values, Wq, Wk, Wv, bq, bk, bv, Qb, Kb, Vt);
  }
  attn_kernel<<<dim3(H_, NQ_ / 128, B_), 512, 0, stream>>>(Qb, Kb, Vt, gp, out);
}

// Round 10
// 240.861 us; speedup vs baseline: 1.8760x; 1.0147x over previous
//
#include <hip/hip_runtime.h>
#include <hip/hip_bf16.h>
#include <cstdint>

typedef unsigned short ushort_t;
typedef __attribute__((ext_vector_type(8))) short short8;
typedef __attribute__((ext_vector_type(4))) float floatx4;
typedef __attribute__((ext_vector_type(4))) unsigned short ushort4_t;

#define H_   16
#define DKV_ 64
#define DM_  1024
#define B_   2
#define NQ_  2048
#define NK_  2048

// fp32 -> bf16 round-to-nearest-even
__device__ __forceinline__ unsigned short f2bf(float f) {
  union { float f; unsigned int u; } v; v.f = f;
  unsigned int u = v.u;
  return (unsigned short)((u + 0x7fffu + ((u >> 16) & 1u)) >> 16);
}

// Trans ops via compiler-visible intrinsics (NOT inline asm) — R5-proven.
__device__ __forceinline__ float fexp2(float x) { return __builtin_amdgcn_exp2f(x); }
__device__ __forceinline__ float frcp(float x)  { return __builtin_amdgcn_rcpf(x); }

__device__ __forceinline__ floatx4 mfma16(short8 a, short8 b, floatx4 c) {
  return __builtin_amdgcn_mfma_f32_16x16x32_bf16(a, b, c, 0, 0, 0);
}

// async global->LDS, 16B per lane; LDS dest = wave-uniform base + lane*16
__device__ __forceinline__ void gload_lds16(const ushort_t* g, ushort_t* l) {
  __builtin_amdgcn_global_load_lds(
      (const __attribute__((address_space(1))) void*)g,
      (__attribute__((address_space(3))) void*)l, 16, 0, 0);
}

// lgkm-only barrier (R3-proven): drains LDS ops but NOT vmem, so prefetch
// global loads stay in flight across tiles. __syncthreads() would emit
// s_waitcnt vmcnt(0) and drain the gp prefetch every tile.
__device__ __forceinline__ void block_sync_lds() {
  asm volatile("s_waitcnt lgkmcnt(0)" ::: "memory");
  __builtin_amdgcn_s_barrier();
  __builtin_amdgcn_sched_barrier(0);
}

// ---------------- prep: fused cast_x + cast_wt (R10: one launch) ----------
// bid < 1536: X-cast role (identical math to R7-proven cast_x_kernel).
// bid >= 1536: W transpose-cast role (identical to cast_wt_kernel).
// Branch is block-uniform (bid), so the in-branch __syncthreads is safe.
__global__ __launch_bounds__(256) void prep_kernel(
    const float* __restrict__ q, const float* __restrict__ k,
    const float* __restrict__ v,
    const float* __restrict__ Wq, const float* __restrict__ Wk,
    const float* __restrict__ Wv,
    ushort_t* __restrict__ Xdst, ushort_t* __restrict__ WtAll)
{
  __shared__ ushort_t tile[32][33];
  const int bid = blockIdx.x;
  if (bid < 1536) {
    const int t = bid >> 9;                       // 0..2
    const float* src = (t == 0) ? q : (t == 1) ? k : v;
    ushort_t* d = Xdst + (size_t)t * 4096 * 1024;
    const int gid = (bid & 511) * 256 + threadIdx.x;
    #pragma unroll
    for (int u = 0; u < 8; u++) {
      const int i4 = u * 131072 + gid;
      floatx4 f = ((const floatx4*)src)[i4];
      ushort4_t o;
      #pragma unroll
      for (int e = 0; e < 4; e++) o[e] = f2bf(f[e]);
      *(ushort4_t*)&d[(size_t)i4 * 4] = o;
    }
  } else {
    const int b2 = bid - 1536;
    const int t = b2 >> 10;                       // 0..2
    const int rem = b2 & 1023;
    const float* W = (t == 0) ? Wq : (t == 1) ? Wk : Wv;
    ushort_t* Wt = WtAll + (size_t)t * 1024 * 1024;
    const int n0 = (rem & 31) * 32, k0 = (rem >> 5) * 32;
    const int tid = threadIdx.x, r = tid >> 3, c4 = (tid & 7) * 4;
    floatx4 f = *(const floatx4*)&W[(size_t)(k0 + r) * 1024 + n0 + c4];
    #pragma unroll
    for (int e = 0; e < 4; e++) tile[r][c4 + e] = f2bf(f[e]);
    __syncthreads();
    ushort4_t o;
    #pragma unroll
    for (int e = 0; e < 4; e++) o[e] = tile[c4 + e][r];
    *(ushort4_t*)&Wt[(size_t)(n0 + r) * 1024 + k0 + c4] = o;
  }
}

// ---------------- proj v3: double-buffered gload_lds (R8, kept) -----------
__global__ __launch_bounds__(256, 2) void proj_kernel2(
    const ushort_t* __restrict__ Xbf, const ushort_t* __restrict__ WtAll,
    const float* __restrict__ bq, const float* __restrict__ bk,
    const float* __restrict__ bv,
    ushort_t* __restrict__ Qb, ushort_t* __restrict__ Kb, ushort_t* __restrict__ Vt)
{
  const int mode = blockIdx.z;
  const ushort_t* X  = Xbf  + (size_t)mode * 4096 * 1024;
  const ushort_t* Wt = WtAll + (size_t)mode * 1024 * 1024;
  const float* bias  = (mode == 0) ? bq : (mode == 1) ? bk : bv;
  ushort_t* dst      = (mode == 0) ? Qb : (mode == 1) ? Kb : Vt;

  // buf b: SA = SM + b*8192, SB = SM + b*8192 + 4096   (shorts)
  __shared__ ushort_t SM[16384];

  const int tid = threadIdx.x, lane = tid & 63, wid = tid >> 6;
  const int c = lane & 15, g = lane >> 4;
  const int m0 = blockIdx.y * 128, n0 = blockIdx.x * 128;
  const int wm = wid & 1, wn = wid >> 1, mb = wm * 64, nb = wn * 64;
  const int srow = lane >> 2;
  const int schunk = (lane & 3) * 8;

  floatx4 acc[4][4];
  #pragma unroll
  for (int i = 0; i < 4; i++)
    #pragma unroll
    for (int j = 0; j < 4; j++) acc[i][j] = floatx4{0.f, 0.f, 0.f, 0.f};

  // prologue: stage step 0 into buf0
  #pragma unroll
  for (int u = 0; u < 2; u++) {
    const int t = wid * 2 + u;
    gload_lds16(&X [(size_t)(m0 + t * 16 + srow) * 1024 + schunk], &SM[t * 512]);
    gload_lds16(&Wt[(size_t)(n0 + t * 16 + srow) * 1024 + schunk], &SM[4096 + t * 512]);
  }
  __syncthreads();

  for (int step = 0; step < 32; step++) {
    const int cur = step & 1, nxt = cur ^ 1;
    if (step + 1 < 32) {
      const int k1 = (step + 1) * 32;
      #pragma unroll
      for (int u = 0; u < 2; u++) {
        const int t = wid * 2 + u;
        gload_lds16(&X [(size_t)(m0 + t * 16 + srow) * 1024 + k1 + schunk],
                    &SM[nxt * 8192 + t * 512]);
        gload_lds16(&Wt[(size_t)(n0 + t * 16 + srow) * 1024 + k1 + schunk],
                    &SM[nxt * 8192 + 4096 + t * 512]);
      }
    }
    const ushort_t* SA = &SM[cur * 8192];
    const ushort_t* SB = &SM[cur * 8192 + 4096];
    short8 af[4], bfr[4];
    #pragma unroll
    for (int i = 0; i < 4; i++) af[i]  = *(const short8*)&SA[(mb + i * 16 + c) * 32 + g * 8];
    #pragma unroll
    for (int j = 0; j < 4; j++) bfr[j] = *(const short8*)&SB[(nb + j * 16 + c) * 32 + g * 8];
    #pragma unroll
    for (int i = 0; i < 4; i++)
      #pragma unroll
      for (int j = 0; j < 4; j++) acc[i][j] = mfma16(af[i], bfr[j], acc[i][j]);
    __syncthreads();
  }

  const float scale = (mode == 0) ? 0.18033688011112042f : 1.0f;
  ushort_t* EP = SM + wid * 2048;
  const int hh = (n0 + nb) >> 6;

  if (mode != 2) {
    for (int jj = 0; jj < 2; jj++) {
      #pragma unroll
      for (int jt = 0; jt < 2; jt++) {
        const int j = jj * 2 + jt;
        const float bb = bias[n0 + nb + j * 16 + c];
        #pragma unroll
        for (int i = 0; i < 4; i++)
          #pragma unroll
          for (int r = 0; r < 4; r++)
            EP[(i * 16 + g * 4 + r) * 32 + jt * 16 + c] =
                f2bf((acc[i][j][r] + bb) * scale);
      }
      #pragma unroll
      for (int u = 0; u < 8; u++) {
        const int rowl = u * 8 + (lane >> 3);
        ushort4_t vv = *(ushort4_t*)&EP[rowl * 32 + (lane & 7) * 4];
        const int rowg = m0 + mb + rowl;
        const int bb2 = rowg >> 11, nn = rowg & 2047;
        *(ushort4_t*)&dst[((size_t)(bb2 * H_ + hh) * NQ_ + nn) * DKV_ +
                          jj * 32 + (lane & 7) * 4] = vv;
      }
    }
  } else {
    const int bb2 = (m0 + mb) >> 11, nloc = (m0 + mb) & 2047;
    for (int j = 0; j < 4; j++) {
      const float bb = bias[n0 + nb + j * 16 + c];
      #pragma unroll
      for (int i = 0; i < 4; i++) {
        ushort4_t pk;
        #pragma unroll
        for (int r = 0; r < 4; r++) pk[r] = f2bf(acc[i][j][r] + bb);
        *(ushort4_t*)&EP[c * 72 + i * 16 + g * 4] = pk;
      }
      const int d0 = j * 16;
      #pragma unroll
      for (int u = 0; u < 2; u++) {
        const int coll = u * 8 + (lane >> 3);
        short8 vv = *(const short8*)&EP[coll * 72 + (lane & 7) * 8];
        *(short8*)&dst[((size_t)(bb2 * H_ + hh) * DKV_ + d0 + coll) * NK_ +
                       nloc + (lane & 7) * 8] = vv;
      }
    }
  }
}

// ---------------- proj fallback (R2/R5-proven) ----------------------------
constexpr int LDT = 40;
__global__ __launch_bounds__(256, 2) void proj_kernel_fb(
    const float* __restrict__ Xq, const float* __restrict__ Xk, const float* __restrict__ Xv,
    const float* __restrict__ Wq, const float* __restrict__ Wk, const float* __restrict__ Wv,
    const float* __restrict__ bq, const float* __restrict__ bk, const float* __restrict__ bv,
    ushort_t* __restrict__ Qb, ushort_t* __restrict__ Kb, ushort_t* __restrict__ Vt)
{
  const int mode = blockIdx.z;
  const float* X    = (mode == 0) ? Xq : (mode == 1) ? Xk : Xv;
  const float* W    = (mode == 0) ? Wq : (mode == 1) ? Wk : Wv;
  const float* bias = (mode == 0) ? bq : (mode == 1) ? bk : bv;
  ushort_t* dst     = (mode == 0) ? Qb : (mode == 1) ? Kb : Vt;

  __shared__ ushort_t Asm[128 * LDT];
  __shared__ ushort_t Bsm[128 * LDT];

  const int tid = threadIdx.x, lane = tid & 63, wid = tid >> 6;
  const int m0 = blockIdx.y * 128, n0 = blockIdx.x * 128;
  const int c = lane & 15, g = lane >> 4;
  const int wm = wid & 1, wn = wid >> 1, mb = wm * 64, nb = wn * 64;

  floatx4 acc[4][4];
  #pragma unroll
  for (int i = 0; i < 4; i++)
    #pragma unroll
    for (int j = 0; j < 4; j++) acc[i][j] = floatx4{0.f, 0.f, 0.f, 0.f};

  const int ar = tid >> 1, ah = tid & 1;
  const int bn = tid & 127, bh2 = tid >> 7;

  for (int k0 = 0; k0 < DM_; k0 += 32) {
    const floatx4* ap = (const floatx4*)(X + (size_t)(m0 + ar) * DM_ + k0 + ah * 16);
    floatx4 av0 = ap[0], av1 = ap[1], av2 = ap[2], av3 = ap[3];
    const float* wp = W + (size_t)(k0 + bh2 * 16) * 1024 + n0 + bn;
    float wv[16];
    #pragma unroll
    for (int j = 0; j < 16; j++) wv[j] = wp[j * 1024];
    short8 pa0, pa1, pb0, pb1;
    #pragma unroll
    for (int j = 0; j < 4; j++) {
      pa0[j] = (short)f2bf(av0[j]); pa0[4 + j] = (short)f2bf(av1[j]);
      pa1[j] = (short)f2bf(av2[j]); pa1[4 + j] = (short)f2bf(av3[j]);
    }
    #pragma unroll
    for (int j = 0; j < 8; j++) { pb0[j] = (short)f2bf(wv[j]); pb1[j] = (short)f2bf(wv[8 + j]); }
    __syncthreads();
    *(short8*)&Asm[ar * LDT + ah * 16]      = pa0;
    *(short8*)&Asm[ar * LDT + ah * 16 + 8]  = pa1;
    *(short8*)&Bsm[bn * LDT + bh2 * 16]     = pb0;
    *(short8*)&Bsm[bn * LDT + bh2 * 16 + 8] = pb1;
    __syncthreads();
    short8 af[4], bfr[4];
    #pragma unroll
    for (int i = 0; i < 4; i++) af[i]  = *(const short8*)&Asm[(mb + i * 16 + c) * LDT + g * 8];
    #pragma unroll
    for (int j = 0; j < 4; j++) bfr[j] = *(const short8*)&Bsm[(nb + j * 16 + c) * LDT + g * 8];
    #pragma unroll
    for (int i = 0; i < 4; i++)
      #pragma unroll
      for (int j = 0; j < 4; j++) acc[i][j] = mfma16(af[i], bfr[j], acc[i][j]);
  }
  #pragma unroll
  for (int j = 0; j < 4; j++) {
    const int col = n0 + nb + j * 16 + c;
    const float bv_ = bias[col];
    const int h = col >> 6, d = col & 63;
    #pragma unroll
    for (int i = 0; i < 4; i++)
      #pragma unroll
      for (int r = 0; r < 4; r++) {
        const int row = m0 + mb + i * 16 + g * 4 + r;
        const int b = row >> 11, n = row & 2047;
        float v = acc[i][j][r] + bv_;
        if (mode == 0) {
          v *= 0.18033688011112042f;
          dst[((size_t)(b * H_ + h) * NQ_ + n) * DKV_ + d] = f2bf(v);
        } else if (mode == 1) {
          dst[((size_t)(b * H_ + h) * NQ_ + n) * DKV_ + d] = f2bf(v);
        } else {
          dst[((size_t)(b * H_ + h) * DKV_ + d) * NK_ + n] = f2bf(v);
        }
      }
  }
}

// ---------------- attn v13: v12 + T5 setprio around MFMA clusters ---------
// R9: gp ping-pong + lgkm barrier = 89.2 -> 85.5 (prediction matched).
// v13 adds only s_setprio(1/0) around the S-cluster and PV-cluster: v12's
// schedule (counted vmem in flight, per-wave phase drift between barriers)
// is closer to the m218b/m224 favorable regime than m190's lockstep null.
// Single remaining cheap lever; everything else audited and excluded
// (3-buf K/V races at odd tiles, 4-buf over LDS budget, occupancy
// grid-capped, conflicts shown benign 2-way-counted).
__global__ __launch_bounds__(512, 4) void attn_kernel(
    const ushort_t* __restrict__ Qb, const ushort_t* __restrict__ Kb,
    const ushort_t* __restrict__ Vt, const float* __restrict__ gp,
    float* __restrict__ out)
{
  __shared__ ushort_t Ks[2][64 * 72];
  __shared__ ushort_t Vs[2][64 * 72];
  __shared__ ushort_t Pl[8][16 * 72];

  constexpr int NT = NK_ / 64;                    // 32 tiles

  const int tid = threadIdx.x, lane = tid & 63, wid = tid >> 6;  // wid 0..7
  const int c = lane & 15, g = lane >> 4;
  const int h = blockIdx.x, b = blockIdx.z;       // h fastest: gp L2 locality
  const int bh = b * H_ + h;
  const int qw = blockIdx.y * 128 + wid * 16;

  const ushort_t* Qp = Qb + (size_t)bh * NQ_ * DKV_;
  const ushort_t* Kp = Kb + (size_t)bh * NK_ * DKV_;
  const ushort_t* Vp = Vt + (size_t)bh * DKV_ * NK_;
  const float* gpp = gp + (size_t)b * NQ_ * NK_ + (size_t)qw * NK_;
  ushort_t* Pw = Pl[wid];

  const int gx16 = (g >> 1) << 4;                 // write-side granule XOR
  const int prd  = g ^ (((c >> 3) & 1) << 1);     // read-side swizzled g

  // cooperative staging: 512 threads cover 64x64, 1 chunk each for K and V
  const int srow = tid >> 3;                      // 0..63
  const int scol = (tid & 7) * 8;                 // 0..56

  // Q fragments resident (pre-scaled by log2(e)/8)
  short8 qf[2];
  #pragma unroll
  for (int kc = 0; kc < 2; kc++)
    qf[kc] = *(const short8*)&Qp[(qw + c) * DKV_ + kc * 32 + g * 8];

  // stage tile 0; gp(0) into gpA
  *(short8*)&Ks[0][srow * 72 + scol] = *(const short8*)&Kp[(size_t)srow * DKV_ + scol];
  *(short8*)&Vs[0][srow * 72 + scol] = *(const short8*)&Vp[(size_t)srow * NK_ + scol];
  float gpA[4][4], gpB[4][4];
  #pragma unroll
  for (int r = 0; r < 4; r++) {
    const float* gq = gpp + (size_t)(g * 4 + r) * NK_ + c;
    #pragma unroll
    for (int jk = 0; jk < 4; jk++) gpA[jk][r] = gq[jk * 16];
  }
  __syncthreads();   // one-time full drain

  floatx4 o[4];
  float l[4];
  #pragma unroll
  for (int jd = 0; jd < 4; jd++) o[jd] = floatx4{0.f, 0.f, 0.f, 0.f};
  #pragma unroll
  for (int r = 0; r < 4; r++) l[r] = 0.f;

  // body: compute tile T from LDS[CUR], gate with GPC (loaded last tile);
  // issue stage(T+1) then gp(T+1)->GPN; commit stage; lgkm-only barrier.
#define ATTN_BODY(T, CUR, GPC, GPN)                                          \
  {                                                                          \
    const int t_ = (T);                                                      \
    const int k0 = t_ * 64;                                                  \
    const bool hn = (t_ + 1) < NT;                                           \
    /* stage loads FIRST (older in vmem queue than gp) */                    \
    short8 knx, vnx;                                                         \
    if (hn) {                                                                \
      const int k1 = k0 + 64;                                                \
      knx = *(const short8*)&Kp[(size_t)(k1 + srow) * DKV_ + scol];          \
      vnx = *(const short8*)&Vp[(size_t)srow * NK_ + k1 + scol];             \
    }                                                                        \
    /* gp(t+1) into GPN (consumed next tile; survives the lgkm barrier) */   \
    if (hn) {                                                                \
      const int k1 = k0 + 64;                                                \
      _Pragma("unroll")                                                      \
      for (int r = 0; r < 4; r++) {                                          \
        const float* gq = gpp + (size_t)(g * 4 + r) * NK_ + k1 + c;          \
        _Pragma("unroll")                                                    \
        for (int jk = 0; jk < 4; jk++) GPN[jk][r] = gq[jk * 16];             \
      }                                                                      \
    }                                                                        \
    /* S = Q K^T (log2 domain), K from LDS */                                \
    floatx4 s_[4];                                                           \
    _Pragma("unroll")                                                        \
    for (int jk = 0; jk < 4; jk++) s_[jk] = floatx4{0.f, 0.f, 0.f, 0.f};     \
    __builtin_amdgcn_s_setprio(1);                                           \
    _Pragma("unroll")                                                        \
    for (int jk = 0; jk < 4; jk++)                                           \
      _Pragma("unroll")                                                      \
      for (int kc = 0; kc < 2; kc++) {                                       \
        short8 kf = *(const short8*)&Ks[CUR][(jk * 16 + c) * 72 + kc * 32 + g * 8]; \
        s_[jk] = mfma16(qf[kc], kf, s_[jk]);                                 \
      }                                                                      \
    __builtin_amdgcn_s_setprio(0);                                           \
    /* p = exp2(s); per-lane l; gate by GPC; P -> LDS (swizzled) */          \
    _Pragma("unroll")                                                        \
    for (int jk = 0; jk < 4; jk++) {                                         \
      const int colw = (jk << 4) ^ gx16;                                     \
      _Pragma("unroll")                                                      \
      for (int r = 0; r < 4; r++) {                                          \
        const float p = fexp2(s_[jk][r]);                                    \
        l[r] += p;                                                           \
        Pw[(g * 4 + r) * 72 + colw + c] = f2bf(p * GPC[jk][r]);              \
      }                                                                      \
    }                                                                        \
    /* PV: A = P rows (swizzled read), B = V from LDS */                     \
    __builtin_amdgcn_s_setprio(1);                                           \
    _Pragma("unroll")                                                        \
    for (int kc = 0; kc < 2; kc++) {                                         \
      short8 af = *(const short8*)&Pw[c * 72 + kc * 32 + prd * 8];           \
      _Pragma("unroll")                                                      \
      for (int jd = 0; jd < 4; jd++) {                                       \
        short8 vf = *(const short8*)&Vs[CUR][(jd * 16 + c) * 72 + kc * 32 + g * 8]; \
        o[jd] = mfma16(af, vf, o[jd]);                                       \
      }                                                                      \
    }                                                                        \
    __builtin_amdgcn_s_setprio(0);                                           \
    /* commit tile t+1 (vmcnt auto-counted on knx/vnx; gp stays in flight)*/ \
    if (hn) {                                                                \
      *(short8*)&Ks[(CUR) ^ 1][srow * 72 + scol] = knx;                      \
      *(short8*)&Vs[(CUR) ^ 1][srow * 72 + scol] = vnx;                      \
    }                                                                        \
    block_sync_lds();                                                        \
  }

  for (int tt = 0; tt < NT; tt += 2) {
    ATTN_BODY(tt,     0, gpA, gpB)
    ATTN_BODY(tt + 1, 1, gpB, gpA)
  }
#undef ATTN_BODY

  // l-reduction across the 16 c-lanes (once per kernel)
  float invl[4];
  #pragma unroll
  for (int r = 0; r < 4; r++) {
    float rs = l[r];
    rs += __shfl_xor(rs, 1);
    rs += __shfl_xor(rs, 2);
    rs += __shfl_xor(rs, 4);
    rs += __shfl_xor(rs, 8);
    invl[r] = frcp(rs);
  }
  #pragma unroll
  for (int jd = 0; jd < 4; jd++)
    #pragma unroll
    for (int r = 0; r < 4; r++) {
      const int row = qw + g * 4 + r;
      out[(size_t)(b * NQ_ + row) * 1024 + h * 64 + jd * 16 + c] =
          o[jd][r] * invl[r];
    }
}

extern "C" void kernel_launch(void* const* d_in, const int* in_sizes, int n_in,
                              void* d_out, int out_size, void* d_ws, size_t ws_size,
                              hipStream_t stream) {
  const float* queries = (const float*)d_in[0];
  const float* keys    = (const float*)d_in[1];
  const float* values  = (const float*)d_in[2];
  const float* gp      = (const float*)d_in[3];
  // d_in[4] attention_mask: intentionally unused (reference discards it)
  const float* Wq = (const float*)d_in[5];
  const float* bq = (const float*)d_in[6];
  const float* Wk = (const float*)d_in[7];
  const float* bk = (const float*)d_in[8];
  const float* Wv = (const float*)d_in[9];
  const float* bv = (const float*)d_in[10];

  const size_t SZ_QKV = (size_t)3 * B_ * H_ * NQ_ * DKV_;  // shorts
  const size_t SZ_X   = (size_t)3 * 4096 * 1024;
  const size_t SZ_W   = (size_t)3 * 1024 * 1024;
  const size_t NEED   = (SZ_QKV + SZ_X + SZ_W) * sizeof(ushort_t);

  ushort_t* Qb = (ushort_t*)d_ws;                       // [B,H,NQ,64] bf16, pre-scaled
  ushort_t* Kb = Qb + (size_t)B_ * H_ * NQ_ * DKV_;     // [B,H,NK,64] bf16
  ushort_t* Vt = Kb + (size_t)B_ * H_ * NK_ * DKV_;     // [B,H,64,NK] bf16
  float* out = (float*)d_out;

  if (ws_size >= NEED) {
    ushort_t* Xbf = Qb + SZ_QKV;
    ushort_t* Wt  = Xbf + SZ_X;
    prep_kernel<<<dim3(4608), 256, 0, stream>>>(
        queries, keys, values, Wq, Wk, Wv, Xbf, Wt);
    proj_kernel2<<<dim3(8, 32, 3), 256, 0, stream>>>(
        Xbf, Wt, bq, bk, bv, Qb, Kb, Vt);
  } else {
    proj_kernel_fb<<<dim3(8, 32, 3), 256, 0, stream>>>(
        queries, keys, values, Wq, Wk, Wv, bq, bk, bv, Qb, Kb, Vt);
  }
  attn_kernel<<<dim3(H_, NQ_ / 128, B_), 512, 0, stream>>>(Qb, Kb, Vt, gp, out);
}